// Round 10
// baseline (726.327 us; speedup 1.0000x reference)
//
#include <hip/hip_runtime.h>
#include <hip/hip_bf16.h>

constexpr int N = 50000;
constexpr int E = 800000;
constexpr int D = 128;
constexpr int H = 4;
constexpr int C = 32;
constexpr int L = 3;
constexpr int E2 = E + N;           // edges + self loops
constexpr float SLOPE = 0.2f;
constexpr float BN_EPS = 1e-5f;
constexpr float LOG2E = 1.4426950408889634f;
constexpr int TILES = (N + 63) / 64;                 // 782 row tiles

typedef __attribute__((ext_vector_type(8))) short bf16x8_t;   // 8 bf16 (4 VGPRs)
typedef __attribute__((ext_vector_type(4))) float f32x4_t;    // MFMA C/D

using hbf = __hip_bfloat16;

__device__ __forceinline__ float fast_exp2(float x) { return __builtin_amdgcn_exp2f(x); }

__device__ __forceinline__ short f2bf(float v) {
    hbf h = __float2bfloat16(v);
    return *reinterpret_cast<short*>(&h);
}
__device__ __forceinline__ float2 bfpair_to_f2(unsigned int u) {
    float2 r;
    r.x = __uint_as_float(u << 16);
    r.y = __uint_as_float(u & 0xffff0000u);
    return r;
}

// ---------- CSR build ----------
__global__ void count_kernel(const int* __restrict__ ei, int* __restrict__ counts) {
    int i = blockIdx.x * blockDim.x + threadIdx.x;
    if (i >= E2) return;
    int dst = (i < E) ? ei[E + i] : (i - E);
    atomicAdd(&counts[dst], 1);
}

__global__ __launch_bounds__(512) void scan_block_kernel(const int* __restrict__ counts,
                                                         int* __restrict__ row_ptr,
                                                         int* __restrict__ blk_sums) {
    __shared__ int s[512];
    int t = threadIdx.x;
    int i = blockIdx.x * 512 + t;
    int v = (i < N) ? counts[i] : 0;
    s[t] = v;
    __syncthreads();
    for (int off = 1; off < 512; off <<= 1) {
        int add = (t >= off) ? s[t - off] : 0;
        __syncthreads();
        s[t] += add;
        __syncthreads();
    }
    if (i < N) row_ptr[i] = s[t] - v;                 // exclusive within block
    if (t == 511) blk_sums[blockIdx.x] = s[511];
}

__global__ __launch_bounds__(128) void scan_sums_kernel(int* __restrict__ blk, int nb) {
    __shared__ int s[128];
    int t = threadIdx.x;
    int v = (t < nb) ? blk[t] : 0;
    s[t] = v;
    __syncthreads();
    for (int off = 1; off < 128; off <<= 1) {
        int add = (t >= off) ? s[t - off] : 0;
        __syncthreads();
        s[t] += add;
        __syncthreads();
    }
    if (t < nb) blk[t] = s[t] - v;                    // exclusive block offsets
}

__global__ void scan_add_kernel(int* __restrict__ row_ptr, const int* __restrict__ blk) {
    int i = blockIdx.x * blockDim.x + threadIdx.x;
    if (i < N) row_ptr[i] += blk[i >> 9];
    if (i == 0) row_ptr[N] = E2;
}

__global__ void scatter_kernel(const int* __restrict__ ei, const int* __restrict__ row_ptr,
                               int* __restrict__ wp, int* __restrict__ col_idx) {
    int i = blockIdx.x * blockDim.x + threadIdx.x;
    if (i >= E2) return;
    int src, dst;
    if (i < E) { src = ei[i]; dst = ei[E + i]; }
    else       { src = i - E; dst = i - E; }
    int pos = row_ptr[dst] + atomicAdd(&wp[dst], 1);
    col_idx[pos] = src;
}

// ---------- pack 10 weight matrices into MFMA B-fragment order (hi bf16 only) ----------
// B frag for 16x16x32: lane holds B[k = ks*32 + (lane>>4)*8 + j][n = nb*16 + (lane&15)],
// j=0..7. Packed index: (mat*2048 + (ks*8+nb)*64 + lane)*8 + j  -> lane-contiguous 16B.
__global__ __launch_bounds__(256) void pack_w_kernel(
        const float* __restrict__ Wl, const float* __restrict__ Wr,
        const float* __restrict__ Wres, const float* __restrict__ Wout,
        hbf* __restrict__ Wph) {
    int gid = blockIdx.x * 256 + threadIdx.x;        // 10 * 16384
    int mat = gid >> 14;
    int d = gid & 16383;
    const float* W;
    if (mat < 3)      W = Wl + (size_t)mat * 16384;
    else if (mat < 6) W = Wr + (size_t)(mat - 3) * 16384;
    else if (mat < 9) W = Wres + (size_t)(mat - 6) * 16384;
    else              W = Wout;
    int j = d & 7, lane = (d >> 3) & 63, nb = (d >> 9) & 7, ks = d >> 12;
    int k = ks * 32 + ((lane >> 4) * 8) + j;
    int n = nb * 16 + (lane & 15);
    Wph[gid] = __float2bfloat16(W[k * D + n]);
}

// ---------- fused 3-matrix MFMA GEMM, one 64-row tile per block ----------
// X = leaky(bn(x)) if sums else x; bn scale/shift derived in-block from sums+gamma+beta.
// xl = bf16(X@Wl), xr = bf16(X@Wr), y = X@Wres + bias.  In-place-safe (x == y): tile
// snapshot into LDS before any store; each tile owned by one block.
// Wave w owns n-blocks {2w, 2w+1}; B frags (24) in VGPRs, loaded once per block.
// 2-term split: X@W ~= Xh@Wh + Xl@Wh (W bf16-rounded).
__global__ __launch_bounds__(256) void gemm3_mfma_kernel(
        const float* x, const float* __restrict__ sums,
        const float* __restrict__ gamma, const float* __restrict__ beta,
        const hbf* __restrict__ Wph,
        int mL, int mR, int mS, const float* __restrict__ bias,
        hbf* __restrict__ xl, hbf* __restrict__ xr, float* y) {
    __shared__ float xs[64][133];                     // +5 pad: 2-way max bank aliasing
    __shared__ float ssl[2][128];                     // bn scale/shift
    int t = threadIdx.x;
    int wave = t >> 6;
    int lane = t & 63;
    int nb0 = wave * 2;                               // this wave's two n-blocks
    int row0 = blockIdx.x * 64;

    if (sums && t < 128) {                            // fold of old bn_finalize
        float mean = sums[t] * (1.0f / N);
        float var = fmaxf(sums[D + t] * (1.0f / N) - mean * mean, 0.f);
        float sc = gamma[t] * rsqrtf(var + BN_EPS);
        ssl[0][t] = sc;
        ssl[1][t] = beta[t] - mean * sc;
    }

    const bf16x8_t* B = (const bf16x8_t*)Wph;
    bf16x8_t bL[4][2], bR[4][2], bS[4][2];            // 24 frags = 96 VGPRs, loaded once
#pragma unroll
    for (int ks = 0; ks < 4; ++ks)
#pragma unroll
        for (int j = 0; j < 2; ++j) {
            int bo = (ks * 8 + nb0 + j) * 64 + lane;
            bL[ks][j] = B[mL * 2048 + bo];
            bR[ks][j] = B[mR * 2048 + bo];
            bS[ks][j] = B[mS * 2048 + bo];
        }
    __syncthreads();                                  // ssl visible

    int cg = (t & 31) * 4;                            // staging col group
    {
        float sc_[4] = {1.f, 1.f, 1.f, 1.f}, sh_[4] = {0.f, 0.f, 0.f, 0.f};
        if (sums) {
#pragma unroll
            for (int j = 0; j < 4; ++j) { sc_[j] = ssl[0][cg + j]; sh_[j] = ssl[1][cg + j]; }
        }
        const float4* x4 = (const float4*)(x + (size_t)row0 * D);
        for (int i = t; i < 64 * 32; i += 256) {
            int r = i >> 5;
            float4 v = make_float4(0.f, 0.f, 0.f, 0.f);
            if (row0 + r < N) {
                v = x4[i];
                if (sums) {
                    v.x = fmaf(v.x, sc_[0], sh_[0]); v.x = fmaxf(v.x, SLOPE * v.x);
                    v.y = fmaf(v.y, sc_[1], sh_[1]); v.y = fmaxf(v.y, SLOPE * v.y);
                    v.z = fmaf(v.z, sc_[2], sh_[2]); v.z = fmaxf(v.z, SLOPE * v.z);
                    v.w = fmaf(v.w, sc_[3], sh_[3]); v.w = fmaxf(v.w, SLOPE * v.w);
                }
            }
            *(float4*)&xs[r][cg] = v;
        }
    }
    __syncthreads();

    int col = lane & 15;
    int koff = (lane >> 4) * 8;
    for (int mm = 0; mm < 4; ++mm) {
        int mrow = mm * 16 + (lane & 15);
        f32x4_t aL[2], aR[2], aS[2];
#pragma unroll
        for (int j = 0; j < 2; ++j) {
            aL[j] = (f32x4_t)0.f; aR[j] = (f32x4_t)0.f; aS[j] = (f32x4_t)0.f;
        }
#pragma unroll
        for (int ks = 0; ks < 4; ++ks) {
            const float* src = &xs[mrow][ks * 32 + koff];
            float4 f0 = *(const float4*)src;
            float4 f1 = *(const float4*)(src + 4);
            float f[8] = {f0.x, f0.y, f0.z, f0.w, f1.x, f1.y, f1.z, f1.w};
            bf16x8_t ah, al;
#pragma unroll
            for (int j = 0; j < 8; ++j) {
                short hi = f2bf(f[j]);
                unsigned int hu = ((unsigned int)(unsigned short)hi) << 16;
                ah[j] = hi;
                al[j] = f2bf(f[j] - __uint_as_float(hu));
            }
#pragma unroll
            for (int j = 0; j < 2; ++j) {
                aL[j] = __builtin_amdgcn_mfma_f32_16x16x32_bf16(ah, bL[ks][j], aL[j], 0, 0, 0);
                aL[j] = __builtin_amdgcn_mfma_f32_16x16x32_bf16(al, bL[ks][j], aL[j], 0, 0, 0);
                aR[j] = __builtin_amdgcn_mfma_f32_16x16x32_bf16(ah, bR[ks][j], aR[j], 0, 0, 0);
                aR[j] = __builtin_amdgcn_mfma_f32_16x16x32_bf16(al, bR[ks][j], aR[j], 0, 0, 0);
                aS[j] = __builtin_amdgcn_mfma_f32_16x16x32_bf16(ah, bS[ks][j], aS[j], 0, 0, 0);
                aS[j] = __builtin_amdgcn_mfma_f32_16x16x32_bf16(al, bS[ks][j], aS[j], 0, 0, 0);
            }
        }
        // C/D layout: col = lane&15, row = (lane>>4)*4 + r
        int rowq = row0 + mm * 16 + (lane >> 4) * 4;
#pragma unroll
        for (int j = 0; j < 2; ++j) {
            int n = (nb0 + j) * 16 + col;
            float bv = bias[n];
#pragma unroll
            for (int r = 0; r < 4; ++r) {
                int row = rowq + r;
                if (row < N) {
                    xl[(size_t)row * D + n] = __float2bfloat16(aL[j][r]);
                    xr[(size_t)row * D + n] = __float2bfloat16(aR[j][r]);
                    y[(size_t)row * D + n]  = aS[j][r] + bv;
                }
            }
        }
    }
}

// ---------- final linear via MFMA, same structure (BN+leaky on load) ----------
__global__ __launch_bounds__(256) void gemm_out_mfma_kernel(
        const float* __restrict__ x, const float* __restrict__ sums,
        const float* __restrict__ gamma, const float* __restrict__ beta,
        const hbf* __restrict__ Wph, const float* __restrict__ b,
        float* __restrict__ out) {
    __shared__ float xs[64][133];
    __shared__ float ssl[2][128];
    int t = threadIdx.x;
    int wave = t >> 6;
    int lane = t & 63;
    int nb0 = wave * 2;
    int row0 = blockIdx.x * 64;

    if (t < 128) {
        float mean = sums[t] * (1.0f / N);
        float var = fmaxf(sums[D + t] * (1.0f / N) - mean * mean, 0.f);
        float sc = gamma[t] * rsqrtf(var + BN_EPS);
        ssl[0][t] = sc;
        ssl[1][t] = beta[t] - mean * sc;
    }

    const bf16x8_t* B = (const bf16x8_t*)Wph + 9 * 2048;      // matrix 9 = Wout
    bf16x8_t bW[4][2];
#pragma unroll
    for (int ks = 0; ks < 4; ++ks)
#pragma unroll
        for (int j = 0; j < 2; ++j)
            bW[ks][j] = B[(ks * 8 + nb0 + j) * 64 + lane];
    __syncthreads();

    int cg = (t & 31) * 4;
    {
        float sc_[4], sh_[4];
#pragma unroll
        for (int j = 0; j < 4; ++j) { sc_[j] = ssl[0][cg + j]; sh_[j] = ssl[1][cg + j]; }
        const float4* x4 = (const float4*)(x + (size_t)row0 * D);
        for (int i = t; i < 64 * 32; i += 256) {
            int r = i >> 5;
            float4 v = make_float4(0.f, 0.f, 0.f, 0.f);
            if (row0 + r < N) {
                v = x4[i];
                v.x = fmaf(v.x, sc_[0], sh_[0]); v.x = fmaxf(v.x, SLOPE * v.x);
                v.y = fmaf(v.y, sc_[1], sh_[1]); v.y = fmaxf(v.y, SLOPE * v.y);
                v.z = fmaf(v.z, sc_[2], sh_[2]); v.z = fmaxf(v.z, SLOPE * v.z);
                v.w = fmaf(v.w, sc_[3], sh_[3]); v.w = fmaxf(v.w, SLOPE * v.w);
            }
            *(float4*)&xs[r][cg] = v;
        }
    }
    __syncthreads();

    int col = lane & 15;
    int koff = (lane >> 4) * 8;
    for (int mm = 0; mm < 4; ++mm) {
        int mrow = mm * 16 + (lane & 15);
        f32x4_t acc[2];
        acc[0] = (f32x4_t)0.f; acc[1] = (f32x4_t)0.f;
#pragma unroll
        for (int ks = 0; ks < 4; ++ks) {
            const float* src = &xs[mrow][ks * 32 + koff];
            float4 f0 = *(const float4*)src;
            float4 f1 = *(const float4*)(src + 4);
            float f[8] = {f0.x, f0.y, f0.z, f0.w, f1.x, f1.y, f1.z, f1.w};
            bf16x8_t ah, al;
#pragma unroll
            for (int j = 0; j < 8; ++j) {
                short hi = f2bf(f[j]);
                unsigned int hu = ((unsigned int)(unsigned short)hi) << 16;
                ah[j] = hi;
                al[j] = f2bf(f[j] - __uint_as_float(hu));
            }
#pragma unroll
            for (int j = 0; j < 2; ++j) {
                acc[j] = __builtin_amdgcn_mfma_f32_16x16x32_bf16(ah, bW[ks][j], acc[j], 0, 0, 0);
                acc[j] = __builtin_amdgcn_mfma_f32_16x16x32_bf16(al, bW[ks][j], acc[j], 0, 0, 0);
            }
        }
        int rowq = row0 + mm * 16 + (lane >> 4) * 4;
#pragma unroll
        for (int j = 0; j < 2; ++j) {
            int n = (nb0 + j) * 16 + col;
            float bv = b[n];
#pragma unroll
            for (int r = 0; r < 4; ++r) {
                int row = rowq + r;
                if (row < N) out[(size_t)row * D + n] = acc[j][r] + bv;
            }
        }
    }
}

// ---------- GATv2 aggregation: wave/node, bf16 gathers, 8-deep SW pipeline ----------
// Edge e lives in slot (e-beg)&7; loop consumes 4 while prefetching 4 at distance 8.
// Scores in log2 domain (att pre-scaled by log2e) -> exp2.
__global__ __launch_bounds__(256) void gat_kernel(
        const hbf* __restrict__ xl, const hbf* __restrict__ xr,
        float* y, const int* __restrict__ row_ptr,
        const int* __restrict__ col_idx, const float* __restrict__ att) {
    int wave = threadIdx.x >> 6;
    int lane = threadIdx.x & 63;
    int v = blockIdx.x * 4 + wave;
    const unsigned int* xlp = (const unsigned int*)xl;        // bf16 pair per lane
    const unsigned int* xrp = (const unsigned int*)xr;
    float2 xr_v = bfpair_to_f2(xrp[(size_t)v * 64 + lane]);
    float2 a2 = ((const float2*)att)[lane];           // channels 2l,2l+1; head = lane/16
    a2.x *= LOG2E; a2.y *= LOG2E;
    int beg = row_ptr[v], end = row_ptr[v + 1];
    float m = -INFINITY, l = 0.f;
    float2 acc = make_float2(0.f, 0.f);

    unsigned int u[8];
#pragma unroll
    for (int k = 0; k < 8; ++k)
        u[k] = (beg + k < end) ? xlp[(size_t)col_idx[beg + k] * 64 + lane] : 0u;

    int idx = beg;
    int phase = 0;
    for (; idx + 3 < end; idx += 4) {
        unsigned int* cur = &u[phase * 4];
        float2 x0 = bfpair_to_f2(cur[0]);
        float2 x1 = bfpair_to_f2(cur[1]);
        float2 x2 = bfpair_to_f2(cur[2]);
        float2 x3 = bfpair_to_f2(cur[3]);
#pragma unroll
        for (int k = 0; k < 4; ++k) {                 // prefetch at distance 8
            int nx = idx + 8 + k;
            if (nx < end) cur[k] = xlp[(size_t)col_idx[nx] * 64 + lane];
        }
        float2 p0, p1, p2, p3;
        p0.x = x0.x + xr_v.x; p0.y = x0.y + xr_v.y;
        p1.x = x1.x + xr_v.x; p1.y = x1.y + xr_v.y;
        p2.x = x2.x + xr_v.x; p2.y = x2.y + xr_v.y;
        p3.x = x3.x + xr_v.x; p3.y = x3.y + xr_v.y;
        p0.x = fmaxf(p0.x, SLOPE * p0.x); p0.y = fmaxf(p0.y, SLOPE * p0.y);
        p1.x = fmaxf(p1.x, SLOPE * p1.x); p1.y = fmaxf(p1.y, SLOPE * p1.y);
        p2.x = fmaxf(p2.x, SLOPE * p2.x); p2.y = fmaxf(p2.y, SLOPE * p2.y);
        p3.x = fmaxf(p3.x, SLOPE * p3.x); p3.y = fmaxf(p3.y, SLOPE * p3.y);
        float s0 = fmaf(p0.x, a2.x, p0.y * a2.y);
        float s1 = fmaf(p1.x, a2.x, p1.y * a2.y);
        float s2 = fmaf(p2.x, a2.x, p2.y * a2.y);
        float s3 = fmaf(p3.x, a2.x, p3.y * a2.y);
        s0 += __shfl_xor(s0, 1); s1 += __shfl_xor(s1, 1);
        s2 += __shfl_xor(s2, 1); s3 += __shfl_xor(s3, 1);
        s0 += __shfl_xor(s0, 2); s1 += __shfl_xor(s1, 2);
        s2 += __shfl_xor(s2, 2); s3 += __shfl_xor(s3, 2);
        s0 += __shfl_xor(s0, 4); s1 += __shfl_xor(s1, 4);
        s2 += __shfl_xor(s2, 4); s3 += __shfl_xor(s3, 4);
        s0 += __shfl_xor(s0, 8); s1 += __shfl_xor(s1, 8);
        s2 += __shfl_xor(s2, 8); s3 += __shfl_xor(s3, 8);
        float nm = fmaxf(fmaxf(m, fmaxf(s0, s1)), fmaxf(s2, s3));
        float scl = fast_exp2(m - nm);                // 0 on first iter (m=-inf)
        float w0 = fast_exp2(s0 - nm);
        float w1 = fast_exp2(s1 - nm);
        float w2 = fast_exp2(s2 - nm);
        float w3 = fast_exp2(s3 - nm);
        l = fmaf(l, scl, (w0 + w1) + (w2 + w3));
        acc.x = fmaf(w3, x3.x, fmaf(w2, x2.x, fmaf(w1, x1.x, fmaf(w0, x0.x, acc.x * scl))));
        acc.y = fmaf(w3, x3.y, fmaf(w2, x2.y, fmaf(w1, x1.y, fmaf(w0, x0.y, acc.y * scl))));
        m = nm;
        phase ^= 1;
    }
    for (; idx < end; ++idx) {                        // tail 0-3 edges, slot (idx-beg)&7
        float2 xa = bfpair_to_f2(u[(idx - beg) & 7]);
        float2 pa;
        pa.x = xa.x + xr_v.x; pa.y = xa.y + xr_v.y;
        pa.x = fmaxf(pa.x, SLOPE * pa.x); pa.y = fmaxf(pa.y, SLOPE * pa.y);
        float sa = fmaf(pa.x, a2.x, pa.y * a2.y);
        sa += __shfl_xor(sa, 1);
        sa += __shfl_xor(sa, 2);
        sa += __shfl_xor(sa, 4);
        sa += __shfl_xor(sa, 8);
        float nm = fmaxf(m, sa);
        float scl = fast_exp2(m - nm);
        float wa  = fast_exp2(sa - nm);
        l = fmaf(l, scl, wa);
        acc.x = fmaf(wa, xa.x, acc.x * scl);
        acc.y = fmaf(wa, xa.y, acc.y * scl);
        m = nm;
    }
    float rl = 1.f / l;
    size_t o = (size_t)v * 64 + lane;
    float2 yv = ((const float2*)y)[o];
    yv.x = fmaf(acc.x, rl, yv.x);                     // agg + res(+bias)
    yv.y = fmaf(acc.y, rl, yv.y);
    ((float2*)y)[o] = yv;
}

// ---------- BatchNorm stats: coalesced float4, LDS reduce, atomics ----------
__global__ __launch_bounds__(256) void bn_stats_kernel(const float* __restrict__ y,
                                                       float* __restrict__ sums) {
    __shared__ float ls[256][4];
    __shared__ float ls2[256][4];
    int t = threadIdx.x;
    float4 s = make_float4(0.f, 0.f, 0.f, 0.f);
    float4 s2 = make_float4(0.f, 0.f, 0.f, 0.f);
    const float4* y4 = (const float4*)y;
    for (int i = blockIdx.x * 256 + t; i < N * D / 4; i += gridDim.x * 256) {
        float4 v = y4[i];                             // cols 4*(t&31)..+3 (fixed)
        s.x += v.x; s.y += v.y; s.z += v.z; s.w += v.w;
        s2.x = fmaf(v.x, v.x, s2.x); s2.y = fmaf(v.y, v.y, s2.y);
        s2.z = fmaf(v.z, v.z, s2.z); s2.w = fmaf(v.w, v.w, s2.w);
    }
    ls[t][0] = s.x;  ls[t][1] = s.y;  ls[t][2] = s.z;  ls[t][3] = s.w;
    ls2[t][0] = s2.x; ls2[t][1] = s2.y; ls2[t][2] = s2.z; ls2[t][3] = s2.w;
    __syncthreads();
    if (t < D) {
        int g = t >> 2, e = t & 3;
        float a = 0.f, b = 0.f;
#pragma unroll
        for (int j = 0; j < 8; ++j) {
            a += ls[g + 32 * j][e];
            b += ls2[g + 32 * j][e];
        }
        atomicAdd(&sums[t], a);
        atomicAdd(&sums[D + t], b);
    }
}

extern "C" void kernel_launch(void* const* d_in, const int* in_sizes, int n_in,
                              void* d_out, int out_size, void* d_ws, size_t ws_size,
                              hipStream_t stream) {
    const float* x_in  = (const float*)d_in[0];
    const int*   ei    = (const int*)d_in[1];
    const float* Wl    = (const float*)d_in[2];
    const float* Wr    = (const float*)d_in[3];
    const float* att   = (const float*)d_in[4];
    const float* bias  = (const float*)d_in[5];
    const float* Wres  = (const float*)d_in[6];
    const float* gamma = (const float*)d_in[7];
    const float* beta  = (const float*)d_in[8];
    const float* Wout  = (const float*)d_in[9];
    const float* bout  = (const float*)d_in[10];
    float* out = (float*)d_out;

    char* ws = (char*)d_ws;
    size_t off = 0;
    auto alloc = [&](size_t bytes) {
        void* p = ws + off;
        off = (off + bytes + 255) & ~(size_t)255;
        return p;
    };
    hbf*   xl       = (hbf*)alloc((size_t)N * D * sizeof(hbf));
    hbf*   xr       = (hbf*)alloc((size_t)N * D * sizeof(hbf));
    float* y        = (float*)alloc((size_t)N * D * sizeof(float));
    hbf*   Wph      = (hbf*)alloc((size_t)10 * D * D * sizeof(hbf));
    int*   row_ptr  = (int*)alloc((size_t)(N + 1) * sizeof(int));
    int*   col_idx  = (int*)alloc((size_t)E2 * sizeof(int));
    int*   counts   = (int*)alloc((size_t)N * sizeof(int));   // reused as write ptr
    int*   blk_sums = (int*)alloc(128 * sizeof(int));
    float* sums     = (float*)alloc(3 * 2 * D * sizeof(float));  // per-layer bn sums

    const int NB = (N + 511) / 512;                  // 98 scan blocks

    // CSR build + weight packing (+ one upfront zero of all 3 bn-sum buffers)
    (void)hipMemsetAsync(counts, 0, (size_t)N * sizeof(int), stream);
    (void)hipMemsetAsync(sums, 0, 3 * 2 * D * sizeof(float), stream);
    count_kernel<<<(E2 + 255) / 256, 256, 0, stream>>>(ei, counts);
    pack_w_kernel<<<10 * 16384 / 256, 256, 0, stream>>>(Wl, Wr, Wres, Wout, Wph);
    scan_block_kernel<<<NB, 512, 0, stream>>>(counts, row_ptr, blk_sums);
    scan_sums_kernel<<<1, 128, 0, stream>>>(blk_sums, NB);
    scan_add_kernel<<<(N + 255) / 256, 256, 0, stream>>>(row_ptr, blk_sums);
    (void)hipMemsetAsync(counts, 0, (size_t)N * sizeof(int), stream);
    scatter_kernel<<<(E2 + 255) / 256, 256, 0, stream>>>(ei, row_ptr, counts, col_idx);

    for (int i = 0; i < L; ++i) {
        const float* xin = (i == 0) ? x_in : y;      // in-place (tile snapshot) for 1,2
        const float* sm  = (i == 0) ? nullptr : sums + (size_t)(i - 1) * 2 * D;
        const float* ga  = (i == 0) ? nullptr : gamma + (size_t)(i - 1) * D;
        const float* be  = (i == 0) ? nullptr : beta + (size_t)(i - 1) * D;
        gemm3_mfma_kernel<<<TILES, 256, 0, stream>>>(xin, sm, ga, be, Wph,
                                                     i, 3 + i, 6 + i,
                                                     bias + (size_t)i * D, xl, xr, y);
        gat_kernel<<<N / 4, 256, 0, stream>>>(xl, xr, y, row_ptr, col_idx,
                                              att + (size_t)i * H * C);
        bn_stats_kernel<<<512, 256, 0, stream>>>(y, sums + (size_t)i * 2 * D);
    }

    gemm_out_mfma_kernel<<<TILES, 256, 0, stream>>>(y, sums + (size_t)2 * 2 * D,
                                                    gamma + (size_t)2 * D,
                                                    beta + (size_t)2 * D, Wph, bout, out);
}

// Round 11
// 594.772 us; speedup vs baseline: 1.2212x; 1.2212x over previous
//
#include <hip/hip_runtime.h>
#include <hip/hip_bf16.h>

constexpr int N = 50000;
constexpr int E = 800000;
constexpr int D = 128;
constexpr int H = 4;
constexpr int C = 32;
constexpr int L = 3;
constexpr int E2 = E + N;           // edges + self loops
constexpr float SLOPE = 0.2f;
constexpr float BN_EPS = 1e-5f;
constexpr float LOG2E = 1.4426950408889634f;
constexpr int TILES = (N + 63) / 64;                 // 782 row tiles

typedef __attribute__((ext_vector_type(8))) short bf16x8_t;   // 8 bf16 (4 VGPRs)
typedef __attribute__((ext_vector_type(4))) float f32x4_t;    // MFMA C/D

using hbf = __hip_bfloat16;

__device__ __forceinline__ float fast_exp2(float x) { return __builtin_amdgcn_exp2f(x); }

__device__ __forceinline__ short f2bf(float v) {
    hbf h = __float2bfloat16(v);
    return *reinterpret_cast<short*>(&h);
}
__device__ __forceinline__ float2 bfpair_to_f2(unsigned int u) {
    float2 r;
    r.x = __uint_as_float(u << 16);
    r.y = __uint_as_float(u & 0xffff0000u);
    return r;
}

// ---------- CSR build ----------
__global__ void count_kernel(const int* __restrict__ ei, int* __restrict__ counts) {
    int i = blockIdx.x * blockDim.x + threadIdx.x;
    if (i >= E2) return;
    int dst = (i < E) ? ei[E + i] : (i - E);
    atomicAdd(&counts[dst], 1);
}

__global__ __launch_bounds__(512) void scan_block_kernel(const int* __restrict__ counts,
                                                         int* __restrict__ row_ptr,
                                                         int* __restrict__ blk_sums) {
    __shared__ int s[512];
    int t = threadIdx.x;
    int i = blockIdx.x * 512 + t;
    int v = (i < N) ? counts[i] : 0;
    s[t] = v;
    __syncthreads();
    for (int off = 1; off < 512; off <<= 1) {
        int add = (t >= off) ? s[t - off] : 0;
        __syncthreads();
        s[t] += add;
        __syncthreads();
    }
    if (i < N) row_ptr[i] = s[t] - v;                 // exclusive within block
    if (t == 511) blk_sums[blockIdx.x] = s[511];
}

__global__ __launch_bounds__(128) void scan_sums_kernel(int* __restrict__ blk, int nb) {
    __shared__ int s[128];
    int t = threadIdx.x;
    int v = (t < nb) ? blk[t] : 0;
    s[t] = v;
    __syncthreads();
    for (int off = 1; off < 128; off <<= 1) {
        int add = (t >= off) ? s[t - off] : 0;
        __syncthreads();
        s[t] += add;
        __syncthreads();
    }
    if (t < nb) blk[t] = s[t] - v;                    // exclusive block offsets
}

__global__ void scan_add_kernel(int* __restrict__ row_ptr, const int* __restrict__ blk) {
    int i = blockIdx.x * blockDim.x + threadIdx.x;
    if (i < N) row_ptr[i] += blk[i >> 9];
    if (i == 0) row_ptr[N] = E2;
}

__global__ void scatter_kernel(const int* __restrict__ ei, const int* __restrict__ row_ptr,
                               int* __restrict__ wp, int* __restrict__ col_idx) {
    int i = blockIdx.x * blockDim.x + threadIdx.x;
    if (i >= E2) return;
    int src, dst;
    if (i < E) { src = ei[i]; dst = ei[E + i]; }
    else       { src = i - E; dst = i - E; }
    int pos = row_ptr[dst] + atomicAdd(&wp[dst], 1);
    col_idx[pos] = src;
}

// ---------- pack 10 weight matrices into MFMA B-fragment order (hi bf16 only) ----------
// B frag for 16x16x32: lane holds B[k = ks*32 + (lane>>4)*8 + j][n = nb*16 + (lane&15)],
// j=0..7. Packed index: (mat*2048 + (ks*8+nb)*64 + lane)*8 + j  -> lane-contiguous 16B.
__global__ __launch_bounds__(256) void pack_w_kernel(
        const float* __restrict__ Wl, const float* __restrict__ Wr,
        const float* __restrict__ Wres, const float* __restrict__ Wout,
        hbf* __restrict__ Wph) {
    int gid = blockIdx.x * 256 + threadIdx.x;        // 10 * 16384
    int mat = gid >> 14;
    int d = gid & 16383;
    const float* W;
    if (mat < 3)      W = Wl + (size_t)mat * 16384;
    else if (mat < 6) W = Wr + (size_t)(mat - 3) * 16384;
    else if (mat < 9) W = Wres + (size_t)(mat - 6) * 16384;
    else              W = Wout;
    int j = d & 7, lane = (d >> 3) & 63, nb = (d >> 9) & 7, ks = d >> 12;
    int k = ks * 32 + ((lane >> 4) * 8) + j;
    int n = nb * 16 + (lane & 15);
    Wph[gid] = __float2bfloat16(W[k * D + n]);
}

// ---------- fused 3-matrix MFMA GEMM, one 64-row tile per block ----------
// X = leaky(bn(x)) if sums else x; bn scale/shift derived in-block from sums+gamma+beta.
// xl = bf16(X@Wl), xr = bf16(X@Wr), y = X@Wres + bias.  In-place-safe (x == y): tile
// snapshot into LDS before any store; each tile owned by one block.
// Wave w owns n-blocks {2w, 2w+1}; B frags (24) in VGPRs, loaded once per block.
// 2-term split: X@W ~= Xh@Wh + Xl@Wh (W bf16-rounded).
__global__ __launch_bounds__(256) void gemm3_mfma_kernel(
        const float* x, const float* __restrict__ sums,
        const float* __restrict__ gamma, const float* __restrict__ beta,
        const hbf* __restrict__ Wph,
        int mL, int mR, int mS, const float* __restrict__ bias,
        hbf* __restrict__ xl, hbf* __restrict__ xr, float* y) {
    __shared__ float xs[64][133];                     // +5 pad: 2-way max bank aliasing
    __shared__ float ssl[2][128];                     // bn scale/shift
    int t = threadIdx.x;
    int wave = t >> 6;
    int lane = t & 63;
    int nb0 = wave * 2;                               // this wave's two n-blocks
    int row0 = blockIdx.x * 64;

    if (sums && t < 128) {                            // fold of old bn_finalize
        float mean = sums[t] * (1.0f / N);
        float var = fmaxf(sums[D + t] * (1.0f / N) - mean * mean, 0.f);
        float sc = gamma[t] * rsqrtf(var + BN_EPS);
        ssl[0][t] = sc;
        ssl[1][t] = beta[t] - mean * sc;
    }

    const bf16x8_t* B = (const bf16x8_t*)Wph;
    bf16x8_t bL[4][2], bR[4][2], bS[4][2];            // 24 frags = 96 VGPRs, loaded once
#pragma unroll
    for (int ks = 0; ks < 4; ++ks)
#pragma unroll
        for (int j = 0; j < 2; ++j) {
            int bo = (ks * 8 + nb0 + j) * 64 + lane;
            bL[ks][j] = B[mL * 2048 + bo];
            bR[ks][j] = B[mR * 2048 + bo];
            bS[ks][j] = B[mS * 2048 + bo];
        }
    __syncthreads();                                  // ssl visible

    int cg = (t & 31) * 4;                            // staging col group
    {
        float sc_[4] = {1.f, 1.f, 1.f, 1.f}, sh_[4] = {0.f, 0.f, 0.f, 0.f};
        if (sums) {
#pragma unroll
            for (int j = 0; j < 4; ++j) { sc_[j] = ssl[0][cg + j]; sh_[j] = ssl[1][cg + j]; }
        }
        const float4* x4 = (const float4*)(x + (size_t)row0 * D);
        for (int i = t; i < 64 * 32; i += 256) {
            int r = i >> 5;
            float4 v = make_float4(0.f, 0.f, 0.f, 0.f);
            if (row0 + r < N) {
                v = x4[i];
                if (sums) {
                    v.x = fmaf(v.x, sc_[0], sh_[0]); v.x = fmaxf(v.x, SLOPE * v.x);
                    v.y = fmaf(v.y, sc_[1], sh_[1]); v.y = fmaxf(v.y, SLOPE * v.y);
                    v.z = fmaf(v.z, sc_[2], sh_[2]); v.z = fmaxf(v.z, SLOPE * v.z);
                    v.w = fmaf(v.w, sc_[3], sh_[3]); v.w = fmaxf(v.w, SLOPE * v.w);
                }
            }
            *(float4*)&xs[r][cg] = v;
        }
    }
    __syncthreads();

    int col = lane & 15;
    int koff = (lane >> 4) * 8;
    for (int mm = 0; mm < 4; ++mm) {
        int mrow = mm * 16 + (lane & 15);
        f32x4_t aL[2], aR[2], aS[2];
#pragma unroll
        for (int j = 0; j < 2; ++j) {
            aL[j] = (f32x4_t)0.f; aR[j] = (f32x4_t)0.f; aS[j] = (f32x4_t)0.f;
        }
#pragma unroll
        for (int ks = 0; ks < 4; ++ks) {
            const float* src = &xs[mrow][ks * 32 + koff];
            float4 f0 = *(const float4*)src;
            float4 f1 = *(const float4*)(src + 4);
            float f[8] = {f0.x, f0.y, f0.z, f0.w, f1.x, f1.y, f1.z, f1.w};
            bf16x8_t ah, al;
#pragma unroll
            for (int j = 0; j < 8; ++j) {
                short hi = f2bf(f[j]);
                unsigned int hu = ((unsigned int)(unsigned short)hi) << 16;
                ah[j] = hi;
                al[j] = f2bf(f[j] - __uint_as_float(hu));
            }
#pragma unroll
            for (int j = 0; j < 2; ++j) {
                aL[j] = __builtin_amdgcn_mfma_f32_16x16x32_bf16(ah, bL[ks][j], aL[j], 0, 0, 0);
                aL[j] = __builtin_amdgcn_mfma_f32_16x16x32_bf16(al, bL[ks][j], aL[j], 0, 0, 0);
                aR[j] = __builtin_amdgcn_mfma_f32_16x16x32_bf16(ah, bR[ks][j], aR[j], 0, 0, 0);
                aR[j] = __builtin_amdgcn_mfma_f32_16x16x32_bf16(al, bR[ks][j], aR[j], 0, 0, 0);
                aS[j] = __builtin_amdgcn_mfma_f32_16x16x32_bf16(ah, bS[ks][j], aS[j], 0, 0, 0);
                aS[j] = __builtin_amdgcn_mfma_f32_16x16x32_bf16(al, bS[ks][j], aS[j], 0, 0, 0);
            }
        }
        // C/D layout: col = lane&15, row = (lane>>4)*4 + r
        int rowq = row0 + mm * 16 + (lane >> 4) * 4;
#pragma unroll
        for (int j = 0; j < 2; ++j) {
            int n = (nb0 + j) * 16 + col;
            float bv = bias[n];
#pragma unroll
            for (int r = 0; r < 4; ++r) {
                int row = rowq + r;
                if (row < N) {
                    xl[(size_t)row * D + n] = __float2bfloat16(aL[j][r]);
                    xr[(size_t)row * D + n] = __float2bfloat16(aR[j][r]);
                    y[(size_t)row * D + n]  = aS[j][r] + bv;
                }
            }
        }
    }
}

// ---------- final linear via MFMA, same structure (BN+leaky on load) ----------
__global__ __launch_bounds__(256) void gemm_out_mfma_kernel(
        const float* __restrict__ x, const float* __restrict__ sums,
        const float* __restrict__ gamma, const float* __restrict__ beta,
        const hbf* __restrict__ Wph, const float* __restrict__ b,
        float* __restrict__ out) {
    __shared__ float xs[64][133];
    __shared__ float ssl[2][128];
    int t = threadIdx.x;
    int wave = t >> 6;
    int lane = t & 63;
    int nb0 = wave * 2;
    int row0 = blockIdx.x * 64;

    if (t < 128) {
        float mean = sums[t] * (1.0f / N);
        float var = fmaxf(sums[D + t] * (1.0f / N) - mean * mean, 0.f);
        float sc = gamma[t] * rsqrtf(var + BN_EPS);
        ssl[0][t] = sc;
        ssl[1][t] = beta[t] - mean * sc;
    }

    const bf16x8_t* B = (const bf16x8_t*)Wph + 9 * 2048;      // matrix 9 = Wout
    bf16x8_t bW[4][2];
#pragma unroll
    for (int ks = 0; ks < 4; ++ks)
#pragma unroll
        for (int j = 0; j < 2; ++j)
            bW[ks][j] = B[(ks * 8 + nb0 + j) * 64 + lane];
    __syncthreads();

    int cg = (t & 31) * 4;
    {
        float sc_[4], sh_[4];
#pragma unroll
        for (int j = 0; j < 4; ++j) { sc_[j] = ssl[0][cg + j]; sh_[j] = ssl[1][cg + j]; }
        const float4* x4 = (const float4*)(x + (size_t)row0 * D);
        for (int i = t; i < 64 * 32; i += 256) {
            int r = i >> 5;
            float4 v = make_float4(0.f, 0.f, 0.f, 0.f);
            if (row0 + r < N) {
                v = x4[i];
                v.x = fmaf(v.x, sc_[0], sh_[0]); v.x = fmaxf(v.x, SLOPE * v.x);
                v.y = fmaf(v.y, sc_[1], sh_[1]); v.y = fmaxf(v.y, SLOPE * v.y);
                v.z = fmaf(v.z, sc_[2], sh_[2]); v.z = fmaxf(v.z, SLOPE * v.z);
                v.w = fmaf(v.w, sc_[3], sh_[3]); v.w = fmaxf(v.w, SLOPE * v.w);
            }
            *(float4*)&xs[r][cg] = v;
        }
    }
    __syncthreads();

    int col = lane & 15;
    int koff = (lane >> 4) * 8;
    for (int mm = 0; mm < 4; ++mm) {
        int mrow = mm * 16 + (lane & 15);
        f32x4_t acc[2];
        acc[0] = (f32x4_t)0.f; acc[1] = (f32x4_t)0.f;
#pragma unroll
        for (int ks = 0; ks < 4; ++ks) {
            const float* src = &xs[mrow][ks * 32 + koff];
            float4 f0 = *(const float4*)src;
            float4 f1 = *(const float4*)(src + 4);
            float f[8] = {f0.x, f0.y, f0.z, f0.w, f1.x, f1.y, f1.z, f1.w};
            bf16x8_t ah, al;
#pragma unroll
            for (int j = 0; j < 8; ++j) {
                short hi = f2bf(f[j]);
                unsigned int hu = ((unsigned int)(unsigned short)hi) << 16;
                ah[j] = hi;
                al[j] = f2bf(f[j] - __uint_as_float(hu));
            }
#pragma unroll
            for (int j = 0; j < 2; ++j) {
                acc[j] = __builtin_amdgcn_mfma_f32_16x16x32_bf16(ah, bW[ks][j], acc[j], 0, 0, 0);
                acc[j] = __builtin_amdgcn_mfma_f32_16x16x32_bf16(al, bW[ks][j], acc[j], 0, 0, 0);
            }
        }
        int rowq = row0 + mm * 16 + (lane >> 4) * 4;
#pragma unroll
        for (int j = 0; j < 2; ++j) {
            int n = (nb0 + j) * 16 + col;
            float bv = b[n];
#pragma unroll
            for (int r = 0; r < 4; ++r) {
                int row = rowq + r;
                if (row < N) out[(size_t)row * D + n] = acc[j][r] + bv;
            }
        }
    }
}

// ---------- GATv2 aggregation: wave/node, bf16 gathers, 8-deep SW pipeline ----------
// Two FIXED 4-slot register buffers, loop body unrolled 2x (no dynamic indexing —
// r10's u[phase*4] pointer demoted the array to LDS: 8KB LDS, 13.7M bank conflicts,
// gat 82->127us). Tail edges reload straight from global (L2-warm).
// Scores in log2 domain (att pre-scaled by log2e) -> exp2.
__global__ __launch_bounds__(256) void gat_kernel(
        const hbf* __restrict__ xl, const hbf* __restrict__ xr,
        float* y, const int* __restrict__ row_ptr,
        const int* __restrict__ col_idx, const float* __restrict__ att) {
    int wave = threadIdx.x >> 6;
    int lane = threadIdx.x & 63;
    int v = blockIdx.x * 4 + wave;
    const unsigned int* xlp = (const unsigned int*)xl;        // bf16 pair per lane
    const unsigned int* xrp = (const unsigned int*)xr;
    float2 xr_v = bfpair_to_f2(xrp[(size_t)v * 64 + lane]);
    float2 a2 = ((const float2*)att)[lane];           // channels 2l,2l+1; head = lane/16
    a2.x *= LOG2E; a2.y *= LOG2E;
    int beg = row_ptr[v], end = row_ptr[v + 1];
    float m = -INFINITY, l = 0.f;
    float2 acc = make_float2(0.f, 0.f);

    unsigned int u0[4], u1[4];
#pragma unroll
    for (int k = 0; k < 4; ++k)
        u0[k] = (beg + k < end) ? xlp[(size_t)col_idx[beg + k] * 64 + lane] : 0u;
#pragma unroll
    for (int k = 0; k < 4; ++k)
        u1[k] = (beg + 4 + k < end) ? xlp[(size_t)col_idx[beg + 4 + k] * 64 + lane] : 0u;

    int idx = beg;
    auto process4 = [&](unsigned int (&buf)[4]) {
        float2 x0 = bfpair_to_f2(buf[0]);
        float2 x1 = bfpair_to_f2(buf[1]);
        float2 x2 = bfpair_to_f2(buf[2]);
        float2 x3 = bfpair_to_f2(buf[3]);
#pragma unroll
        for (int k = 0; k < 4; ++k) {                 // prefetch at distance 8
            int nx = idx + 8 + k;
            if (nx < end) buf[k] = xlp[(size_t)col_idx[nx] * 64 + lane];
        }
        float2 p0, p1, p2, p3;
        p0.x = x0.x + xr_v.x; p0.y = x0.y + xr_v.y;
        p1.x = x1.x + xr_v.x; p1.y = x1.y + xr_v.y;
        p2.x = x2.x + xr_v.x; p2.y = x2.y + xr_v.y;
        p3.x = x3.x + xr_v.x; p3.y = x3.y + xr_v.y;
        p0.x = fmaxf(p0.x, SLOPE * p0.x); p0.y = fmaxf(p0.y, SLOPE * p0.y);
        p1.x = fmaxf(p1.x, SLOPE * p1.x); p1.y = fmaxf(p1.y, SLOPE * p1.y);
        p2.x = fmaxf(p2.x, SLOPE * p2.x); p2.y = fmaxf(p2.y, SLOPE * p2.y);
        p3.x = fmaxf(p3.x, SLOPE * p3.x); p3.y = fmaxf(p3.y, SLOPE * p3.y);
        float s0 = fmaf(p0.x, a2.x, p0.y * a2.y);
        float s1 = fmaf(p1.x, a2.x, p1.y * a2.y);
        float s2 = fmaf(p2.x, a2.x, p2.y * a2.y);
        float s3 = fmaf(p3.x, a2.x, p3.y * a2.y);
        s0 += __shfl_xor(s0, 1); s1 += __shfl_xor(s1, 1);
        s2 += __shfl_xor(s2, 1); s3 += __shfl_xor(s3, 1);
        s0 += __shfl_xor(s0, 2); s1 += __shfl_xor(s1, 2);
        s2 += __shfl_xor(s2, 2); s3 += __shfl_xor(s3, 2);
        s0 += __shfl_xor(s0, 4); s1 += __shfl_xor(s1, 4);
        s2 += __shfl_xor(s2, 4); s3 += __shfl_xor(s3, 4);
        s0 += __shfl_xor(s0, 8); s1 += __shfl_xor(s1, 8);
        s2 += __shfl_xor(s2, 8); s3 += __shfl_xor(s3, 8);
        float nm = fmaxf(fmaxf(m, fmaxf(s0, s1)), fmaxf(s2, s3));
        float scl = fast_exp2(m - nm);                // 0 on first iter (m=-inf)
        float w0 = fast_exp2(s0 - nm);
        float w1 = fast_exp2(s1 - nm);
        float w2 = fast_exp2(s2 - nm);
        float w3 = fast_exp2(s3 - nm);
        l = fmaf(l, scl, (w0 + w1) + (w2 + w3));
        acc.x = fmaf(w3, x3.x, fmaf(w2, x2.x, fmaf(w1, x1.x, fmaf(w0, x0.x, acc.x * scl))));
        acc.y = fmaf(w3, x3.y, fmaf(w2, x2.y, fmaf(w1, x1.y, fmaf(w0, x0.y, acc.y * scl))));
        m = nm;
    };

    while (idx + 3 < end) {
        process4(u0);
        idx += 4;
        if (idx + 3 >= end) break;
        process4(u1);
        idx += 4;
    }
    for (; idx < end; ++idx) {                        // tail <=3 edges: reload (L2-warm)
        float2 xa = bfpair_to_f2(xlp[(size_t)col_idx[idx] * 64 + lane]);
        float2 pa;
        pa.x = xa.x + xr_v.x; pa.y = xa.y + xr_v.y;
        pa.x = fmaxf(pa.x, SLOPE * pa.x); pa.y = fmaxf(pa.y, SLOPE * pa.y);
        float sa = fmaf(pa.x, a2.x, pa.y * a2.y);
        sa += __shfl_xor(sa, 1);
        sa += __shfl_xor(sa, 2);
        sa += __shfl_xor(sa, 4);
        sa += __shfl_xor(sa, 8);
        float nm = fmaxf(m, sa);
        float scl = fast_exp2(m - nm);
        float wa  = fast_exp2(sa - nm);
        l = fmaf(l, scl, wa);
        acc.x = fmaf(wa, xa.x, acc.x * scl);
        acc.y = fmaf(wa, xa.y, acc.y * scl);
        m = nm;
    }
    float rl = 1.f / l;
    size_t o = (size_t)v * 64 + lane;
    float2 yv = ((const float2*)y)[o];
    yv.x = fmaf(acc.x, rl, yv.x);                     // agg + res(+bias)
    yv.y = fmaf(acc.y, rl, yv.y);
    ((float2*)y)[o] = yv;
}

// ---------- BatchNorm stats: coalesced float4, LDS reduce, atomics ----------
__global__ __launch_bounds__(256) void bn_stats_kernel(const float* __restrict__ y,
                                                       float* __restrict__ sums) {
    __shared__ float ls[256][4];
    __shared__ float ls2[256][4];
    int t = threadIdx.x;
    float4 s = make_float4(0.f, 0.f, 0.f, 0.f);
    float4 s2 = make_float4(0.f, 0.f, 0.f, 0.f);
    const float4* y4 = (const float4*)y;
    for (int i = blockIdx.x * 256 + t; i < N * D / 4; i += gridDim.x * 256) {
        float4 v = y4[i];                             // cols 4*(t&31)..+3 (fixed)
        s.x += v.x; s.y += v.y; s.z += v.z; s.w += v.w;
        s2.x = fmaf(v.x, v.x, s2.x); s2.y = fmaf(v.y, v.y, s2.y);
        s2.z = fmaf(v.z, v.z, s2.z); s2.w = fmaf(v.w, v.w, s2.w);
    }
    ls[t][0] = s.x;  ls[t][1] = s.y;  ls[t][2] = s.z;  ls[t][3] = s.w;
    ls2[t][0] = s2.x; ls2[t][1] = s2.y; ls2[t][2] = s2.z; ls2[t][3] = s2.w;
    __syncthreads();
    if (t < D) {
        int g = t >> 2, e = t & 3;
        float a = 0.f, b = 0.f;
#pragma unroll
        for (int j = 0; j < 8; ++j) {
            a += ls[g + 32 * j][e];
            b += ls2[g + 32 * j][e];
        }
        atomicAdd(&sums[t], a);
        atomicAdd(&sums[D + t], b);
    }
}

extern "C" void kernel_launch(void* const* d_in, const int* in_sizes, int n_in,
                              void* d_out, int out_size, void* d_ws, size_t ws_size,
                              hipStream_t stream) {
    const float* x_in  = (const float*)d_in[0];
    const int*   ei    = (const int*)d_in[1];
    const float* Wl    = (const float*)d_in[2];
    const float* Wr    = (const float*)d_in[3];
    const float* att   = (const float*)d_in[4];
    const float* bias  = (const float*)d_in[5];
    const float* Wres  = (const float*)d_in[6];
    const float* gamma = (const float*)d_in[7];
    const float* beta  = (const float*)d_in[8];
    const float* Wout  = (const float*)d_in[9];
    const float* bout  = (const float*)d_in[10];
    float* out = (float*)d_out;

    char* ws = (char*)d_ws;
    size_t off = 0;
    auto alloc = [&](size_t bytes) {
        void* p = ws + off;
        off = (off + bytes + 255) & ~(size_t)255;
        return p;
    };
    hbf*   xl       = (hbf*)alloc((size_t)N * D * sizeof(hbf));
    hbf*   xr       = (hbf*)alloc((size_t)N * D * sizeof(hbf));
    float* y        = (float*)alloc((size_t)N * D * sizeof(float));
    hbf*   Wph      = (hbf*)alloc((size_t)10 * D * D * sizeof(hbf));
    int*   row_ptr  = (int*)alloc((size_t)(N + 1) * sizeof(int));
    int*   col_idx  = (int*)alloc((size_t)E2 * sizeof(int));
    int*   counts   = (int*)alloc((size_t)N * sizeof(int));   // reused as write ptr
    int*   blk_sums = (int*)alloc(128 * sizeof(int));
    float* sums     = (float*)alloc(3 * 2 * D * sizeof(float));  // per-layer bn sums

    const int NB = (N + 511) / 512;                  // 98 scan blocks

    // CSR build + weight packing (+ one upfront zero of all 3 bn-sum buffers)
    (void)hipMemsetAsync(counts, 0, (size_t)N * sizeof(int), stream);
    (void)hipMemsetAsync(sums, 0, 3 * 2 * D * sizeof(float), stream);
    count_kernel<<<(E2 + 255) / 256, 256, 0, stream>>>(ei, counts);
    pack_w_kernel<<<10 * 16384 / 256, 256, 0, stream>>>(Wl, Wr, Wres, Wout, Wph);
    scan_block_kernel<<<NB, 512, 0, stream>>>(counts, row_ptr, blk_sums);
    scan_sums_kernel<<<1, 128, 0, stream>>>(blk_sums, NB);
    scan_add_kernel<<<(N + 255) / 256, 256, 0, stream>>>(row_ptr, blk_sums);
    (void)hipMemsetAsync(counts, 0, (size_t)N * sizeof(int), stream);
    scatter_kernel<<<(E2 + 255) / 256, 256, 0, stream>>>(ei, row_ptr, counts, col_idx);

    for (int i = 0; i < L; ++i) {
        const float* xin = (i == 0) ? x_in : y;      // in-place (tile snapshot) for 1,2
        const float* sm  = (i == 0) ? nullptr : sums + (size_t)(i - 1) * 2 * D;
        const float* ga  = (i == 0) ? nullptr : gamma + (size_t)(i - 1) * D;
        const float* be  = (i == 0) ? nullptr : beta + (size_t)(i - 1) * D;
        gemm3_mfma_kernel<<<TILES, 256, 0, stream>>>(xin, sm, ga, be, Wph,
                                                     i, 3 + i, 6 + i,
                                                     bias + (size_t)i * D, xl, xr, y);
        gat_kernel<<<N / 4, 256, 0, stream>>>(xl, xr, y, row_ptr, col_idx,
                                              att + (size_t)i * H * C);
        bn_stats_kernel<<<512, 256, 0, stream>>>(y, sums + (size_t)i * 2 * D);
    }

    gemm_out_mfma_kernel<<<TILES, 256, 0, stream>>>(y, sums + (size_t)2 * 2 * D,
                                                    gamma + (size_t)2 * D,
                                                    beta + (size_t)2 * D, Wph, bout, out);
}

// Round 12
// 502.377 us; speedup vs baseline: 1.4458x; 1.1839x over previous
//
#include <hip/hip_runtime.h>
#include <hip/hip_bf16.h>

constexpr int N = 50000;
constexpr int E = 800000;
constexpr int D = 128;
constexpr int H = 4;
constexpr int C = 32;
constexpr int L = 3;
constexpr int E2 = E + N;           // edges + self loops
constexpr float SLOPE = 0.2f;
constexpr float BN_EPS = 1e-5f;
constexpr float LOG2E = 1.4426950408889634f;
constexpr int TILES = (N + 63) / 64;                 // 782 row tiles

typedef __attribute__((ext_vector_type(8))) short bf16x8_t;   // 8 bf16 (4 VGPRs)
typedef __attribute__((ext_vector_type(4))) float f32x4_t;    // MFMA C/D

using hbf = __hip_bfloat16;

__device__ __forceinline__ float fast_exp2(float x) { return __builtin_amdgcn_exp2f(x); }

__device__ __forceinline__ short f2bf(float v) {
    hbf h = __float2bfloat16(v);
    return *reinterpret_cast<short*>(&h);
}
__device__ __forceinline__ float2 bfpair_to_f2(unsigned int u) {
    float2 r;
    r.x = __uint_as_float(u << 16);
    r.y = __uint_as_float(u & 0xffff0000u);
    return r;
}

// ---------- CSR build ----------
__global__ void count_kernel(const int* __restrict__ ei, int* __restrict__ counts) {
    int i = blockIdx.x * blockDim.x + threadIdx.x;
    if (i >= E2) return;
    int dst = (i < E) ? ei[E + i] : (i - E);
    atomicAdd(&counts[dst], 1);
}

__global__ __launch_bounds__(512) void scan_block_kernel(const int* __restrict__ counts,
                                                         int* __restrict__ row_ptr,
                                                         int* __restrict__ blk_sums) {
    __shared__ int s[512];
    int t = threadIdx.x;
    int i = blockIdx.x * 512 + t;
    int v = (i < N) ? counts[i] : 0;
    s[t] = v;
    __syncthreads();
    for (int off = 1; off < 512; off <<= 1) {
        int add = (t >= off) ? s[t - off] : 0;
        __syncthreads();
        s[t] += add;
        __syncthreads();
    }
    if (i < N) row_ptr[i] = s[t] - v;                 // exclusive within block
    if (t == 511) blk_sums[blockIdx.x] = s[511];
}

__global__ __launch_bounds__(128) void scan_sums_kernel(int* __restrict__ blk, int nb) {
    __shared__ int s[128];
    int t = threadIdx.x;
    int v = (t < nb) ? blk[t] : 0;
    s[t] = v;
    __syncthreads();
    for (int off = 1; off < 128; off <<= 1) {
        int add = (t >= off) ? s[t - off] : 0;
        __syncthreads();
        s[t] += add;
        __syncthreads();
    }
    if (t < nb) blk[t] = s[t] - v;                    // exclusive block offsets
}

__global__ void scan_add_kernel(int* __restrict__ row_ptr, const int* __restrict__ blk) {
    int i = blockIdx.x * blockDim.x + threadIdx.x;
    if (i < N) row_ptr[i] += blk[i >> 9];
    if (i == 0) row_ptr[N] = E2;
}

__global__ void scatter_kernel(const int* __restrict__ ei, const int* __restrict__ row_ptr,
                               int* __restrict__ wp, int* __restrict__ col_idx) {
    int i = blockIdx.x * blockDim.x + threadIdx.x;
    if (i >= E2) return;
    int src, dst;
    if (i < E) { src = ei[i]; dst = ei[E + i]; }
    else       { src = i - E; dst = i - E; }
    int pos = row_ptr[dst] + atomicAdd(&wp[dst], 1);
    col_idx[pos] = src;
}

// ---------- pack 10 weight matrices into MFMA B-fragment order (hi bf16 only) ----------
// B frag for 16x16x32: lane holds B[k = ks*32 + (lane>>4)*8 + j][n = nb*16 + (lane&15)],
// j=0..7. Packed index: (mat*2048 + (ks*8+nb)*64 + lane)*8 + j  -> lane-contiguous 16B.
__global__ __launch_bounds__(256) void pack_w_kernel(
        const float* __restrict__ Wl, const float* __restrict__ Wr,
        const float* __restrict__ Wres, const float* __restrict__ Wout,
        hbf* __restrict__ Wph) {
    int gid = blockIdx.x * 256 + threadIdx.x;        // 10 * 16384
    int mat = gid >> 14;
    int d = gid & 16383;
    const float* W;
    if (mat < 3)      W = Wl + (size_t)mat * 16384;
    else if (mat < 6) W = Wr + (size_t)(mat - 3) * 16384;
    else if (mat < 9) W = Wres + (size_t)(mat - 6) * 16384;
    else              W = Wout;
    int j = d & 7, lane = (d >> 3) & 63, nb = (d >> 9) & 7, ks = d >> 12;
    int k = ks * 32 + ((lane >> 4) * 8) + j;
    int n = nb * 16 + (lane & 15);
    Wph[gid] = __float2bfloat16(W[k * D + n]);
}

// ---------- fused 3-matrix MFMA GEMM, one 64-row tile per block ----------
// X = leaky(bn(x)) if sums else x; bn scale/shift derived in-block from sums+gamma+beta.
// xl = bf16(X@Wl), xr = bf16(X@Wr), y = X@Wres + bias.  In-place-safe (x == y): tile
// snapshot into LDS before any store; each tile owned by one block.
// Wave w owns n-blocks {2w, 2w+1}; B frags (24) in VGPRs, loaded once per block.
// 2-term split: X@W ~= Xh@Wh + Xl@Wh (W bf16-rounded).
__global__ __launch_bounds__(256) void gemm3_mfma_kernel(
        const float* x, const float* __restrict__ sums,
        const float* __restrict__ gamma, const float* __restrict__ beta,
        const hbf* __restrict__ Wph,
        int mL, int mR, int mS, const float* __restrict__ bias,
        hbf* __restrict__ xl, hbf* __restrict__ xr, float* y) {
    __shared__ float xs[64][133];                     // +5 pad: 2-way max bank aliasing
    __shared__ float ssl[2][128];                     // bn scale/shift
    int t = threadIdx.x;
    int wave = t >> 6;
    int lane = t & 63;
    int nb0 = wave * 2;                               // this wave's two n-blocks
    int row0 = blockIdx.x * 64;

    if (sums && t < 128) {                            // fold of old bn_finalize
        float mean = sums[t] * (1.0f / N);
        float var = fmaxf(sums[D + t] * (1.0f / N) - mean * mean, 0.f);
        float sc = gamma[t] * rsqrtf(var + BN_EPS);
        ssl[0][t] = sc;
        ssl[1][t] = beta[t] - mean * sc;
    }

    const bf16x8_t* B = (const bf16x8_t*)Wph;
    bf16x8_t bL[4][2], bR[4][2], bS[4][2];            // 24 frags = 96 VGPRs, loaded once
#pragma unroll
    for (int ks = 0; ks < 4; ++ks)
#pragma unroll
        for (int j = 0; j < 2; ++j) {
            int bo = (ks * 8 + nb0 + j) * 64 + lane;
            bL[ks][j] = B[mL * 2048 + bo];
            bR[ks][j] = B[mR * 2048 + bo];
            bS[ks][j] = B[mS * 2048 + bo];
        }
    __syncthreads();                                  // ssl visible

    int cg = (t & 31) * 4;                            // staging col group
    {
        float sc_[4] = {1.f, 1.f, 1.f, 1.f}, sh_[4] = {0.f, 0.f, 0.f, 0.f};
        if (sums) {
#pragma unroll
            for (int j = 0; j < 4; ++j) { sc_[j] = ssl[0][cg + j]; sh_[j] = ssl[1][cg + j]; }
        }
        const float4* x4 = (const float4*)(x + (size_t)row0 * D);
        for (int i = t; i < 64 * 32; i += 256) {
            int r = i >> 5;
            float4 v = make_float4(0.f, 0.f, 0.f, 0.f);
            if (row0 + r < N) {
                v = x4[i];
                if (sums) {
                    v.x = fmaf(v.x, sc_[0], sh_[0]); v.x = fmaxf(v.x, SLOPE * v.x);
                    v.y = fmaf(v.y, sc_[1], sh_[1]); v.y = fmaxf(v.y, SLOPE * v.y);
                    v.z = fmaf(v.z, sc_[2], sh_[2]); v.z = fmaxf(v.z, SLOPE * v.z);
                    v.w = fmaf(v.w, sc_[3], sh_[3]); v.w = fmaxf(v.w, SLOPE * v.w);
                }
            }
            *(float4*)&xs[r][cg] = v;
        }
    }
    __syncthreads();

    int col = lane & 15;
    int koff = (lane >> 4) * 8;
    for (int mm = 0; mm < 4; ++mm) {
        int mrow = mm * 16 + (lane & 15);
        f32x4_t aL[2], aR[2], aS[2];
#pragma unroll
        for (int j = 0; j < 2; ++j) {
            aL[j] = (f32x4_t)0.f; aR[j] = (f32x4_t)0.f; aS[j] = (f32x4_t)0.f;
        }
#pragma unroll
        for (int ks = 0; ks < 4; ++ks) {
            const float* src = &xs[mrow][ks * 32 + koff];
            float4 f0 = *(const float4*)src;
            float4 f1 = *(const float4*)(src + 4);
            float f[8] = {f0.x, f0.y, f0.z, f0.w, f1.x, f1.y, f1.z, f1.w};
            bf16x8_t ah, al;
#pragma unroll
            for (int j = 0; j < 8; ++j) {
                short hi = f2bf(f[j]);
                unsigned int hu = ((unsigned int)(unsigned short)hi) << 16;
                ah[j] = hi;
                al[j] = f2bf(f[j] - __uint_as_float(hu));
            }
#pragma unroll
            for (int j = 0; j < 2; ++j) {
                aL[j] = __builtin_amdgcn_mfma_f32_16x16x32_bf16(ah, bL[ks][j], aL[j], 0, 0, 0);
                aL[j] = __builtin_amdgcn_mfma_f32_16x16x32_bf16(al, bL[ks][j], aL[j], 0, 0, 0);
                aR[j] = __builtin_amdgcn_mfma_f32_16x16x32_bf16(ah, bR[ks][j], aR[j], 0, 0, 0);
                aR[j] = __builtin_amdgcn_mfma_f32_16x16x32_bf16(al, bR[ks][j], aR[j], 0, 0, 0);
                aS[j] = __builtin_amdgcn_mfma_f32_16x16x32_bf16(ah, bS[ks][j], aS[j], 0, 0, 0);
                aS[j] = __builtin_amdgcn_mfma_f32_16x16x32_bf16(al, bS[ks][j], aS[j], 0, 0, 0);
            }
        }
        // C/D layout: col = lane&15, row = (lane>>4)*4 + r
        int rowq = row0 + mm * 16 + (lane >> 4) * 4;
#pragma unroll
        for (int j = 0; j < 2; ++j) {
            int n = (nb0 + j) * 16 + col;
            float bv = bias[n];
#pragma unroll
            for (int r = 0; r < 4; ++r) {
                int row = rowq + r;
                if (row < N) {
                    xl[(size_t)row * D + n] = __float2bfloat16(aL[j][r]);
                    xr[(size_t)row * D + n] = __float2bfloat16(aR[j][r]);
                    y[(size_t)row * D + n]  = aS[j][r] + bv;
                }
            }
        }
    }
}

// ---------- final linear via MFMA, same structure (BN+leaky on load) ----------
__global__ __launch_bounds__(256) void gemm_out_mfma_kernel(
        const float* __restrict__ x, const float* __restrict__ sums,
        const float* __restrict__ gamma, const float* __restrict__ beta,
        const hbf* __restrict__ Wph, const float* __restrict__ b,
        float* __restrict__ out) {
    __shared__ float xs[64][133];
    __shared__ float ssl[2][128];
    int t = threadIdx.x;
    int wave = t >> 6;
    int lane = t & 63;
    int nb0 = wave * 2;
    int row0 = blockIdx.x * 64;

    if (t < 128) {
        float mean = sums[t] * (1.0f / N);
        float var = fmaxf(sums[D + t] * (1.0f / N) - mean * mean, 0.f);
        float sc = gamma[t] * rsqrtf(var + BN_EPS);
        ssl[0][t] = sc;
        ssl[1][t] = beta[t] - mean * sc;
    }

    const bf16x8_t* B = (const bf16x8_t*)Wph + 9 * 2048;      // matrix 9 = Wout
    bf16x8_t bW[4][2];
#pragma unroll
    for (int ks = 0; ks < 4; ++ks)
#pragma unroll
        for (int j = 0; j < 2; ++j)
            bW[ks][j] = B[(ks * 8 + nb0 + j) * 64 + lane];
    __syncthreads();

    int cg = (t & 31) * 4;
    {
        float sc_[4], sh_[4];
#pragma unroll
        for (int j = 0; j < 4; ++j) { sc_[j] = ssl[0][cg + j]; sh_[j] = ssl[1][cg + j]; }
        const float4* x4 = (const float4*)(x + (size_t)row0 * D);
        for (int i = t; i < 64 * 32; i += 256) {
            int r = i >> 5;
            float4 v = make_float4(0.f, 0.f, 0.f, 0.f);
            if (row0 + r < N) {
                v = x4[i];
                v.x = fmaf(v.x, sc_[0], sh_[0]); v.x = fmaxf(v.x, SLOPE * v.x);
                v.y = fmaf(v.y, sc_[1], sh_[1]); v.y = fmaxf(v.y, SLOPE * v.y);
                v.z = fmaf(v.z, sc_[2], sh_[2]); v.z = fmaxf(v.z, SLOPE * v.z);
                v.w = fmaf(v.w, sc_[3], sh_[3]); v.w = fmaxf(v.w, SLOPE * v.w);
            }
            *(float4*)&xs[r][cg] = v;
        }
    }
    __syncthreads();

    int col = lane & 15;
    int koff = (lane >> 4) * 8;
    for (int mm = 0; mm < 4; ++mm) {
        int mrow = mm * 16 + (lane & 15);
        f32x4_t acc[2];
        acc[0] = (f32x4_t)0.f; acc[1] = (f32x4_t)0.f;
#pragma unroll
        for (int ks = 0; ks < 4; ++ks) {
            const float* src = &xs[mrow][ks * 32 + koff];
            float4 f0 = *(const float4*)src;
            float4 f1 = *(const float4*)(src + 4);
            float f[8] = {f0.x, f0.y, f0.z, f0.w, f1.x, f1.y, f1.z, f1.w};
            bf16x8_t ah, al;
#pragma unroll
            for (int j = 0; j < 8; ++j) {
                short hi = f2bf(f[j]);
                unsigned int hu = ((unsigned int)(unsigned short)hi) << 16;
                ah[j] = hi;
                al[j] = f2bf(f[j] - __uint_as_float(hu));
            }
#pragma unroll
            for (int j = 0; j < 2; ++j) {
                acc[j] = __builtin_amdgcn_mfma_f32_16x16x32_bf16(ah, bW[ks][j], acc[j], 0, 0, 0);
                acc[j] = __builtin_amdgcn_mfma_f32_16x16x32_bf16(al, bW[ks][j], acc[j], 0, 0, 0);
            }
        }
        int rowq = row0 + mm * 16 + (lane >> 4) * 4;
#pragma unroll
        for (int j = 0; j < 2; ++j) {
            int n = (nb0 + j) * 16 + col;
            float bv = b[n];
#pragma unroll
            for (int r = 0; r < 4; ++r) {
                int row = rowq + r;
                if (row < N) out[(size_t)row * D + n] = acc[j][r] + bv;
            }
        }
    }
}

// ---------- GATv2 aggregation: wave/node, bf16 gathers, 8-deep SW pipeline ----------
// NO online max: scores are BN-bounded (|s| < ~40 << fp32 exp2 range), so softmax
// is computed as plain l = sum exp2(s), acc = sum exp2(s)*x — removes the serial
// rescale chain that capped r9/r11 at ~82-86us. Two fixed 4-slot register buffers
// (r10 lesson: dynamic indexing demotes to LDS), prefetch distance 8 with
// min-clamped indices (no guard branches; over-prefetch never consumed).
// Scores in log2 domain (att pre-scaled by log2e) -> exp2.
__global__ __launch_bounds__(256) void gat_kernel(
        const hbf* __restrict__ xl, const hbf* __restrict__ xr,
        float* y, const int* __restrict__ row_ptr,
        const int* __restrict__ col_idx, const float* __restrict__ att) {
    int wave = threadIdx.x >> 6;
    int lane = threadIdx.x & 63;
    int v = blockIdx.x * 4 + wave;
    const unsigned int* xlp = (const unsigned int*)xl;        // bf16 pair per lane
    const unsigned int* xrp = (const unsigned int*)xr;
    float2 xr_v = bfpair_to_f2(xrp[(size_t)v * 64 + lane]);
    float2 a2 = ((const float2*)att)[lane];           // channels 2l,2l+1; head = lane/16
    a2.x *= LOG2E; a2.y *= LOG2E;
    int beg = row_ptr[v], end = row_ptr[v + 1];
    float l0 = 0.f, l1 = 0.f;
    float2 acc0 = make_float2(0.f, 0.f);
    float2 acc1 = make_float2(0.f, 0.f);

    unsigned int u0[4], u1[4];
#pragma unroll
    for (int k = 0; k < 4; ++k)
        u0[k] = xlp[(size_t)col_idx[min(beg + k, end - 1)] * 64 + lane];
#pragma unroll
    for (int k = 0; k < 4; ++k)
        u1[k] = xlp[(size_t)col_idx[min(beg + 4 + k, end - 1)] * 64 + lane];

    int idx = beg;
    auto process4 = [&](unsigned int (&buf)[4]) {
        float2 x0 = bfpair_to_f2(buf[0]);
        float2 x1 = bfpair_to_f2(buf[1]);
        float2 x2 = bfpair_to_f2(buf[2]);
        float2 x3 = bfpair_to_f2(buf[3]);
#pragma unroll
        for (int k = 0; k < 4; ++k) {                 // prefetch at distance 8 (clamped)
            int nx = min(idx + 8 + k, end - 1);
            buf[k] = xlp[(size_t)col_idx[nx] * 64 + lane];
        }
        float2 p0, p1, p2, p3;
        p0.x = x0.x + xr_v.x; p0.y = x0.y + xr_v.y;
        p1.x = x1.x + xr_v.x; p1.y = x1.y + xr_v.y;
        p2.x = x2.x + xr_v.x; p2.y = x2.y + xr_v.y;
        p3.x = x3.x + xr_v.x; p3.y = x3.y + xr_v.y;
        p0.x = fmaxf(p0.x, SLOPE * p0.x); p0.y = fmaxf(p0.y, SLOPE * p0.y);
        p1.x = fmaxf(p1.x, SLOPE * p1.x); p1.y = fmaxf(p1.y, SLOPE * p1.y);
        p2.x = fmaxf(p2.x, SLOPE * p2.x); p2.y = fmaxf(p2.y, SLOPE * p2.y);
        p3.x = fmaxf(p3.x, SLOPE * p3.x); p3.y = fmaxf(p3.y, SLOPE * p3.y);
        float s0 = fmaf(p0.x, a2.x, p0.y * a2.y);
        float s1 = fmaf(p1.x, a2.x, p1.y * a2.y);
        float s2 = fmaf(p2.x, a2.x, p2.y * a2.y);
        float s3 = fmaf(p3.x, a2.x, p3.y * a2.y);
        s0 += __shfl_xor(s0, 1); s1 += __shfl_xor(s1, 1);
        s2 += __shfl_xor(s2, 1); s3 += __shfl_xor(s3, 1);
        s0 += __shfl_xor(s0, 2); s1 += __shfl_xor(s1, 2);
        s2 += __shfl_xor(s2, 2); s3 += __shfl_xor(s3, 2);
        s0 += __shfl_xor(s0, 4); s1 += __shfl_xor(s1, 4);
        s2 += __shfl_xor(s2, 4); s3 += __shfl_xor(s3, 4);
        s0 += __shfl_xor(s0, 8); s1 += __shfl_xor(s1, 8);
        s2 += __shfl_xor(s2, 8); s3 += __shfl_xor(s3, 8);
        float w0 = fast_exp2(s0);
        float w1 = fast_exp2(s1);
        float w2 = fast_exp2(s2);
        float w3 = fast_exp2(s3);
        l0 += w0 + w1;
        l1 += w2 + w3;
        acc0.x = fmaf(w1, x1.x, fmaf(w0, x0.x, acc0.x));
        acc0.y = fmaf(w1, x1.y, fmaf(w0, x0.y, acc0.y));
        acc1.x = fmaf(w3, x3.x, fmaf(w2, x2.x, acc1.x));
        acc1.y = fmaf(w3, x3.y, fmaf(w2, x2.y, acc1.y));
    };

    while (idx + 3 < end) {
        process4(u0);
        idx += 4;
        if (idx + 3 >= end) break;
        process4(u1);
        idx += 4;
    }
    for (; idx < end; ++idx) {                        // tail <=3 edges: reload (L2-warm)
        float2 xa = bfpair_to_f2(xlp[(size_t)col_idx[idx] * 64 + lane]);
        float2 pa;
        pa.x = xa.x + xr_v.x; pa.y = xa.y + xr_v.y;
        pa.x = fmaxf(pa.x, SLOPE * pa.x); pa.y = fmaxf(pa.y, SLOPE * pa.y);
        float sa = fmaf(pa.x, a2.x, pa.y * a2.y);
        sa += __shfl_xor(sa, 1);
        sa += __shfl_xor(sa, 2);
        sa += __shfl_xor(sa, 4);
        sa += __shfl_xor(sa, 8);
        float wa = fast_exp2(sa);
        l0 += wa;
        acc0.x = fmaf(wa, xa.x, acc0.x);
        acc0.y = fmaf(wa, xa.y, acc0.y);
    }
    float rl = 1.f / (l0 + l1);
    size_t o = (size_t)v * 64 + lane;
    float2 yv = ((const float2*)y)[o];
    yv.x = fmaf(acc0.x + acc1.x, rl, yv.x);           // agg + res(+bias)
    yv.y = fmaf(acc0.y + acc1.y, rl, yv.y);
    ((float2*)y)[o] = yv;
}

// ---------- BatchNorm stats: coalesced float4, LDS reduce, atomics ----------
__global__ __launch_bounds__(256) void bn_stats_kernel(const float* __restrict__ y,
                                                       float* __restrict__ sums) {
    __shared__ float ls[256][4];
    __shared__ float ls2[256][4];
    int t = threadIdx.x;
    float4 s = make_float4(0.f, 0.f, 0.f, 0.f);
    float4 s2 = make_float4(0.f, 0.f, 0.f, 0.f);
    const float4* y4 = (const float4*)y;
    for (int i = blockIdx.x * 256 + t; i < N * D / 4; i += gridDim.x * 256) {
        float4 v = y4[i];                             // cols 4*(t&31)..+3 (fixed)
        s.x += v.x; s.y += v.y; s.z += v.z; s.w += v.w;
        s2.x = fmaf(v.x, v.x, s2.x); s2.y = fmaf(v.y, v.y, s2.y);
        s2.z = fmaf(v.z, v.z, s2.z); s2.w = fmaf(v.w, v.w, s2.w);
    }
    ls[t][0] = s.x;  ls[t][1] = s.y;  ls[t][2] = s.z;  ls[t][3] = s.w;
    ls2[t][0] = s2.x; ls2[t][1] = s2.y; ls2[t][2] = s2.z; ls2[t][3] = s2.w;
    __syncthreads();
    if (t < D) {
        int g = t >> 2, e = t & 3;
        float a = 0.f, b = 0.f;
#pragma unroll
        for (int j = 0; j < 8; ++j) {
            a += ls[g + 32 * j][e];
            b += ls2[g + 32 * j][e];
        }
        atomicAdd(&sums[t], a);
        atomicAdd(&sums[D + t], b);
    }
}

extern "C" void kernel_launch(void* const* d_in, const int* in_sizes, int n_in,
                              void* d_out, int out_size, void* d_ws, size_t ws_size,
                              hipStream_t stream) {
    const float* x_in  = (const float*)d_in[0];
    const int*   ei    = (const int*)d_in[1];
    const float* Wl    = (const float*)d_in[2];
    const float* Wr    = (const float*)d_in[3];
    const float* att   = (const float*)d_in[4];
    const float* bias  = (const float*)d_in[5];
    const float* Wres  = (const float*)d_in[6];
    const float* gamma = (const float*)d_in[7];
    const float* beta  = (const float*)d_in[8];
    const float* Wout  = (const float*)d_in[9];
    const float* bout  = (const float*)d_in[10];
    float* out = (float*)d_out;

    char* ws = (char*)d_ws;
    size_t off = 0;
    auto alloc = [&](size_t bytes) {
        void* p = ws + off;
        off = (off + bytes + 255) & ~(size_t)255;
        return p;
    };
    hbf*   xl       = (hbf*)alloc((size_t)N * D * sizeof(hbf));
    hbf*   xr       = (hbf*)alloc((size_t)N * D * sizeof(hbf));
    float* y        = (float*)alloc((size_t)N * D * sizeof(float));
    hbf*   Wph      = (hbf*)alloc((size_t)10 * D * D * sizeof(hbf));
    int*   row_ptr  = (int*)alloc((size_t)(N + 1) * sizeof(int));
    int*   col_idx  = (int*)alloc((size_t)E2 * sizeof(int));
    int*   counts   = (int*)alloc((size_t)N * sizeof(int));   // reused as write ptr
    int*   blk_sums = (int*)alloc(128 * sizeof(int));
    float* sums     = (float*)alloc(3 * 2 * D * sizeof(float));  // per-layer bn sums

    const int NB = (N + 511) / 512;                  // 98 scan blocks

    // CSR build + weight packing (+ one upfront zero of all 3 bn-sum buffers)
    (void)hipMemsetAsync(counts, 0, (size_t)N * sizeof(int), stream);
    (void)hipMemsetAsync(sums, 0, 3 * 2 * D * sizeof(float), stream);
    count_kernel<<<(E2 + 255) / 256, 256, 0, stream>>>(ei, counts);
    pack_w_kernel<<<10 * 16384 / 256, 256, 0, stream>>>(Wl, Wr, Wres, Wout, Wph);
    scan_block_kernel<<<NB, 512, 0, stream>>>(counts, row_ptr, blk_sums);
    scan_sums_kernel<<<1, 128, 0, stream>>>(blk_sums, NB);
    scan_add_kernel<<<(N + 255) / 256, 256, 0, stream>>>(row_ptr, blk_sums);
    (void)hipMemsetAsync(counts, 0, (size_t)N * sizeof(int), stream);
    scatter_kernel<<<(E2 + 255) / 256, 256, 0, stream>>>(ei, row_ptr, counts, col_idx);

    for (int i = 0; i < L; ++i) {
        const float* xin = (i == 0) ? x_in : y;      // in-place (tile snapshot) for 1,2
        const float* sm  = (i == 0) ? nullptr : sums + (size_t)(i - 1) * 2 * D;
        const float* ga  = (i == 0) ? nullptr : gamma + (size_t)(i - 1) * D;
        const float* be  = (i == 0) ? nullptr : beta + (size_t)(i - 1) * D;
        gemm3_mfma_kernel<<<TILES, 256, 0, stream>>>(xin, sm, ga, be, Wph,
                                                     i, 3 + i, 6 + i,
                                                     bias + (size_t)i * D, xl, xr, y);
        gat_kernel<<<N / 4, 256, 0, stream>>>(xl, xr, y, row_ptr, col_idx,
                                              att + (size_t)i * H * C);
        bn_stats_kernel<<<512, 256, 0, stream>>>(y, sums + (size_t)i * 2 * D);
    }

    gemm_out_mfma_kernel<<<TILES, 256, 0, stream>>>(y, sums + (size_t)2 * 2 * D,
                                                    gamma + (size_t)2 * D,
                                                    beta + (size_t)2 * D, Wph, bout, out);
}

// Round 13
// 497.848 us; speedup vs baseline: 1.4589x; 1.0091x over previous
//
#include <hip/hip_runtime.h>
#include <hip/hip_bf16.h>

constexpr int N = 50000;
constexpr int E = 800000;
constexpr int D = 128;
constexpr int H = 4;
constexpr int C = 32;
constexpr int L = 3;
constexpr int E2 = E + N;           // edges + self loops
constexpr float SLOPE = 0.2f;
constexpr float BN_EPS = 1e-5f;
constexpr float LOG2E = 1.4426950408889634f;
constexpr int TILES = (N + 63) / 64;                 // 782 row tiles

typedef __attribute__((ext_vector_type(8))) short bf16x8_t;   // 8 bf16 (4 VGPRs)
typedef __attribute__((ext_vector_type(4))) float f32x4_t;    // MFMA C/D
typedef __attribute__((ext_vector_type(2))) float v2f;        // packed fp32 (v_pk_*)

using hbf = __hip_bfloat16;

__device__ __forceinline__ float fast_exp2(float x) { return __builtin_amdgcn_exp2f(x); }

__device__ __forceinline__ short f2bf(float v) {
    hbf h = __float2bfloat16(v);
    return *reinterpret_cast<short*>(&h);
}
__device__ __forceinline__ v2f bfpair_to_v2(unsigned int u) {
    v2f r;
    r.x = __uint_as_float(u << 16);
    r.y = __uint_as_float(u & 0xffff0000u);
    return r;
}

// ---------- CSR build ----------
__global__ void count_kernel(const int* __restrict__ ei, int* __restrict__ counts) {
    int i = blockIdx.x * blockDim.x + threadIdx.x;
    if (i >= E2) return;
    int dst = (i < E) ? ei[E + i] : (i - E);
    atomicAdd(&counts[dst], 1);
}

__global__ __launch_bounds__(512) void scan_block_kernel(const int* __restrict__ counts,
                                                         int* __restrict__ row_ptr,
                                                         int* __restrict__ blk_sums) {
    __shared__ int s[512];
    int t = threadIdx.x;
    int i = blockIdx.x * 512 + t;
    int v = (i < N) ? counts[i] : 0;
    s[t] = v;
    __syncthreads();
    for (int off = 1; off < 512; off <<= 1) {
        int add = (t >= off) ? s[t - off] : 0;
        __syncthreads();
        s[t] += add;
        __syncthreads();
    }
    if (i < N) row_ptr[i] = s[t] - v;                 // exclusive within block
    if (t == 511) blk_sums[blockIdx.x] = s[511];
}

__global__ __launch_bounds__(128) void scan_sums_kernel(int* __restrict__ blk, int nb) {
    __shared__ int s[128];
    int t = threadIdx.x;
    int v = (t < nb) ? blk[t] : 0;
    s[t] = v;
    __syncthreads();
    for (int off = 1; off < 128; off <<= 1) {
        int add = (t >= off) ? s[t - off] : 0;
        __syncthreads();
        s[t] += add;
        __syncthreads();
    }
    if (t < nb) blk[t] = s[t] - v;                    // exclusive block offsets
}

__global__ void scan_add_kernel(int* __restrict__ row_ptr, const int* __restrict__ blk) {
    int i = blockIdx.x * blockDim.x + threadIdx.x;
    if (i < N) row_ptr[i] += blk[i >> 9];
    if (i == 0) row_ptr[N] = E2;
}

__global__ void scatter_kernel(const int* __restrict__ ei, const int* __restrict__ row_ptr,
                               int* __restrict__ wp, int* __restrict__ col_idx) {
    int i = blockIdx.x * blockDim.x + threadIdx.x;
    if (i >= E2) return;
    int src, dst;
    if (i < E) { src = ei[i]; dst = ei[E + i]; }
    else       { src = i - E; dst = i - E; }
    int pos = row_ptr[dst] + atomicAdd(&wp[dst], 1);
    col_idx[pos] = src;
}

// ---------- pack 10 weight matrices into MFMA B-fragment order (hi bf16 only) ----------
// B frag for 16x16x32: lane holds B[k = ks*32 + (lane>>4)*8 + j][n = nb*16 + (lane&15)],
// j=0..7. Packed index: (mat*2048 + (ks*8+nb)*64 + lane)*8 + j  -> lane-contiguous 16B.
__global__ __launch_bounds__(256) void pack_w_kernel(
        const float* __restrict__ Wl, const float* __restrict__ Wr,
        const float* __restrict__ Wres, const float* __restrict__ Wout,
        hbf* __restrict__ Wph) {
    int gid = blockIdx.x * 256 + threadIdx.x;        // 10 * 16384
    int mat = gid >> 14;
    int d = gid & 16383;
    const float* W;
    if (mat < 3)      W = Wl + (size_t)mat * 16384;
    else if (mat < 6) W = Wr + (size_t)(mat - 3) * 16384;
    else if (mat < 9) W = Wres + (size_t)(mat - 6) * 16384;
    else              W = Wout;
    int j = d & 7, lane = (d >> 3) & 63, nb = (d >> 9) & 7, ks = d >> 12;
    int k = ks * 32 + ((lane >> 4) * 8) + j;
    int n = nb * 16 + (lane & 15);
    Wph[gid] = __float2bfloat16(W[k * D + n]);
}

// ---------- fused 3-matrix MFMA GEMM, one 64-row tile per block ----------
// X = leaky(bn(x)) if sums else x; bn scale/shift derived in-block from sums+gamma+beta.
// xl = bf16(X@Wl), xr = bf16(X@Wr), y = X@Wres + bias.  In-place-safe (x == y): tile
// snapshot into LDS before any store; each tile owned by one block.
// Wave w owns n-blocks {2w, 2w+1}; B frags (24) in VGPRs, loaded once per block.
// 2-term split: X@W ~= Xh@Wh + Xl@Wh (W bf16-rounded).
__global__ __launch_bounds__(256) void gemm3_mfma_kernel(
        const float* x, const float* __restrict__ sums,
        const float* __restrict__ gamma, const float* __restrict__ beta,
        const hbf* __restrict__ Wph,
        int mL, int mR, int mS, const float* __restrict__ bias,
        hbf* __restrict__ xl, hbf* __restrict__ xr, float* y) {
    __shared__ float xs[64][133];                     // +5 pad: 2-way max bank aliasing
    __shared__ float ssl[2][128];                     // bn scale/shift
    int t = threadIdx.x;
    int wave = t >> 6;
    int lane = t & 63;
    int nb0 = wave * 2;                               // this wave's two n-blocks
    int row0 = blockIdx.x * 64;

    if (sums && t < 128) {                            // fold of old bn_finalize
        float mean = sums[t] * (1.0f / N);
        float var = fmaxf(sums[D + t] * (1.0f / N) - mean * mean, 0.f);
        float sc = gamma[t] * rsqrtf(var + BN_EPS);
        ssl[0][t] = sc;
        ssl[1][t] = beta[t] - mean * sc;
    }

    const bf16x8_t* B = (const bf16x8_t*)Wph;
    bf16x8_t bL[4][2], bR[4][2], bS[4][2];            // 24 frags = 96 VGPRs, loaded once
#pragma unroll
    for (int ks = 0; ks < 4; ++ks)
#pragma unroll
        for (int j = 0; j < 2; ++j) {
            int bo = (ks * 8 + nb0 + j) * 64 + lane;
            bL[ks][j] = B[mL * 2048 + bo];
            bR[ks][j] = B[mR * 2048 + bo];
            bS[ks][j] = B[mS * 2048 + bo];
        }
    __syncthreads();                                  // ssl visible

    int cg = (t & 31) * 4;                            // staging col group
    {
        float sc_[4] = {1.f, 1.f, 1.f, 1.f}, sh_[4] = {0.f, 0.f, 0.f, 0.f};
        if (sums) {
#pragma unroll
            for (int j = 0; j < 4; ++j) { sc_[j] = ssl[0][cg + j]; sh_[j] = ssl[1][cg + j]; }
        }
        const float4* x4 = (const float4*)(x + (size_t)row0 * D);
        for (int i = t; i < 64 * 32; i += 256) {
            int r = i >> 5;
            float4 v = make_float4(0.f, 0.f, 0.f, 0.f);
            if (row0 + r < N) {
                v = x4[i];
                if (sums) {
                    v.x = fmaf(v.x, sc_[0], sh_[0]); v.x = fmaxf(v.x, SLOPE * v.x);
                    v.y = fmaf(v.y, sc_[1], sh_[1]); v.y = fmaxf(v.y, SLOPE * v.y);
                    v.z = fmaf(v.z, sc_[2], sh_[2]); v.z = fmaxf(v.z, SLOPE * v.z);
                    v.w = fmaf(v.w, sc_[3], sh_[3]); v.w = fmaxf(v.w, SLOPE * v.w);
                }
            }
            *(float4*)&xs[r][cg] = v;
        }
    }
    __syncthreads();

    int col = lane & 15;
    int koff = (lane >> 4) * 8;
    for (int mm = 0; mm < 4; ++mm) {
        int mrow = mm * 16 + (lane & 15);
        f32x4_t aL[2], aR[2], aS[2];
#pragma unroll
        for (int j = 0; j < 2; ++j) {
            aL[j] = (f32x4_t)0.f; aR[j] = (f32x4_t)0.f; aS[j] = (f32x4_t)0.f;
        }
#pragma unroll
        for (int ks = 0; ks < 4; ++ks) {
            const float* src = &xs[mrow][ks * 32 + koff];
            float4 f0 = *(const float4*)src;
            float4 f1 = *(const float4*)(src + 4);
            float f[8] = {f0.x, f0.y, f0.z, f0.w, f1.x, f1.y, f1.z, f1.w};
            bf16x8_t ah, al;
#pragma unroll
            for (int j = 0; j < 8; ++j) {
                short hi = f2bf(f[j]);
                unsigned int hu = ((unsigned int)(unsigned short)hi) << 16;
                ah[j] = hi;
                al[j] = f2bf(f[j] - __uint_as_float(hu));
            }
#pragma unroll
            for (int j = 0; j < 2; ++j) {
                aL[j] = __builtin_amdgcn_mfma_f32_16x16x32_bf16(ah, bL[ks][j], aL[j], 0, 0, 0);
                aL[j] = __builtin_amdgcn_mfma_f32_16x16x32_bf16(al, bL[ks][j], aL[j], 0, 0, 0);
                aR[j] = __builtin_amdgcn_mfma_f32_16x16x32_bf16(ah, bR[ks][j], aR[j], 0, 0, 0);
                aR[j] = __builtin_amdgcn_mfma_f32_16x16x32_bf16(al, bR[ks][j], aR[j], 0, 0, 0);
                aS[j] = __builtin_amdgcn_mfma_f32_16x16x32_bf16(ah, bS[ks][j], aS[j], 0, 0, 0);
                aS[j] = __builtin_amdgcn_mfma_f32_16x16x32_bf16(al, bS[ks][j], aS[j], 0, 0, 0);
            }
        }
        // C/D layout: col = lane&15, row = (lane>>4)*4 + r
        int rowq = row0 + mm * 16 + (lane >> 4) * 4;
#pragma unroll
        for (int j = 0; j < 2; ++j) {
            int n = (nb0 + j) * 16 + col;
            float bv = bias[n];
#pragma unroll
            for (int r = 0; r < 4; ++r) {
                int row = rowq + r;
                if (row < N) {
                    xl[(size_t)row * D + n] = __float2bfloat16(aL[j][r]);
                    xr[(size_t)row * D + n] = __float2bfloat16(aR[j][r]);
                    y[(size_t)row * D + n]  = aS[j][r] + bv;
                }
            }
        }
    }
}

// ---------- final linear via MFMA, same structure (BN+leaky on load) ----------
__global__ __launch_bounds__(256) void gemm_out_mfma_kernel(
        const float* __restrict__ x, const float* __restrict__ sums,
        const float* __restrict__ gamma, const float* __restrict__ beta,
        const hbf* __restrict__ Wph, const float* __restrict__ b,
        float* __restrict__ out) {
    __shared__ float xs[64][133];
    __shared__ float ssl[2][128];
    int t = threadIdx.x;
    int wave = t >> 6;
    int lane = t & 63;
    int nb0 = wave * 2;
    int row0 = blockIdx.x * 64;

    if (t < 128) {
        float mean = sums[t] * (1.0f / N);
        float var = fmaxf(sums[D + t] * (1.0f / N) - mean * mean, 0.f);
        float sc = gamma[t] * rsqrtf(var + BN_EPS);
        ssl[0][t] = sc;
        ssl[1][t] = beta[t] - mean * sc;
    }

    const bf16x8_t* B = (const bf16x8_t*)Wph + 9 * 2048;      // matrix 9 = Wout
    bf16x8_t bW[4][2];
#pragma unroll
    for (int ks = 0; ks < 4; ++ks)
#pragma unroll
        for (int j = 0; j < 2; ++j)
            bW[ks][j] = B[(ks * 8 + nb0 + j) * 64 + lane];
    __syncthreads();

    int cg = (t & 31) * 4;
    {
        float sc_[4], sh_[4];
#pragma unroll
        for (int j = 0; j < 4; ++j) { sc_[j] = ssl[0][cg + j]; sh_[j] = ssl[1][cg + j]; }
        const float4* x4 = (const float4*)(x + (size_t)row0 * D);
        for (int i = t; i < 64 * 32; i += 256) {
            int r = i >> 5;
            float4 v = make_float4(0.f, 0.f, 0.f, 0.f);
            if (row0 + r < N) {
                v = x4[i];
                v.x = fmaf(v.x, sc_[0], sh_[0]); v.x = fmaxf(v.x, SLOPE * v.x);
                v.y = fmaf(v.y, sc_[1], sh_[1]); v.y = fmaxf(v.y, SLOPE * v.y);
                v.z = fmaf(v.z, sc_[2], sh_[2]); v.z = fmaxf(v.z, SLOPE * v.z);
                v.w = fmaf(v.w, sc_[3], sh_[3]); v.w = fmaxf(v.w, SLOPE * v.w);
            }
            *(float4*)&xs[r][cg] = v;
        }
    }
    __syncthreads();

    int col = lane & 15;
    int koff = (lane >> 4) * 8;
    for (int mm = 0; mm < 4; ++mm) {
        int mrow = mm * 16 + (lane & 15);
        f32x4_t acc[2];
        acc[0] = (f32x4_t)0.f; acc[1] = (f32x4_t)0.f;
#pragma unroll
        for (int ks = 0; ks < 4; ++ks) {
            const float* src = &xs[mrow][ks * 32 + koff];
            float4 f0 = *(const float4*)src;
            float4 f1 = *(const float4*)(src + 4);
            float f[8] = {f0.x, f0.y, f0.z, f0.w, f1.x, f1.y, f1.z, f1.w};
            bf16x8_t ah, al;
#pragma unroll
            for (int j = 0; j < 8; ++j) {
                short hi = f2bf(f[j]);
                unsigned int hu = ((unsigned int)(unsigned short)hi) << 16;
                ah[j] = hi;
                al[j] = f2bf(f[j] - __uint_as_float(hu));
            }
#pragma unroll
            for (int j = 0; j < 2; ++j) {
                acc[j] = __builtin_amdgcn_mfma_f32_16x16x32_bf16(ah, bW[ks][j], acc[j], 0, 0, 0);
                acc[j] = __builtin_amdgcn_mfma_f32_16x16x32_bf16(al, bW[ks][j], acc[j], 0, 0, 0);
            }
        }
        int rowq = row0 + mm * 16 + (lane >> 4) * 4;
#pragma unroll
        for (int j = 0; j < 2; ++j) {
            int n = (nb0 + j) * 16 + col;
            float bv = b[n];
#pragma unroll
            for (int r = 0; r < 4; ++r) {
                int row = rowq + r;
                if (row < N) out[(size_t)row * D + n] = acc[j][r] + bv;
            }
        }
    }
}

// ---------- GATv2 aggregation: wave/node, bf16 gathers, 8-deep SW pipeline ----------
// Packed-fp32 channel math (v2f -> v_pk_add/pk_mul/pk_max/pk_fma) — r12 showed
// VALUBusy 80% (issue-bound); packing halves the elementwise instruction count.
// No online max (scores BN-bounded, |s| << fp32 exp2 range). Two fixed 4-slot
// register buffers (r10: dynamic indexing demotes to LDS), prefetch distance 8,
// min-clamped indices. Scores in log2 domain -> exp2.
__global__ __launch_bounds__(256) void gat_kernel(
        const hbf* __restrict__ xl, const hbf* __restrict__ xr,
        float* y, const int* __restrict__ row_ptr,
        const int* __restrict__ col_idx, const float* __restrict__ att) {
    int wave = threadIdx.x >> 6;
    int lane = threadIdx.x & 63;
    int v = blockIdx.x * 4 + wave;
    const unsigned int* xlp = (const unsigned int*)xl;        // bf16 pair per lane
    const unsigned int* xrp = (const unsigned int*)xr;
    v2f xr_v = bfpair_to_v2(xrp[(size_t)v * 64 + lane]);
    float2 a2s = ((const float2*)att)[lane];          // channels 2l,2l+1; head = lane/16
    v2f a2; a2.x = a2s.x * LOG2E; a2.y = a2s.y * LOG2E;
    int beg = row_ptr[v], end = row_ptr[v + 1];
    float l0 = 0.f, l1 = 0.f;
    v2f acc0 = {0.f, 0.f};
    v2f acc1 = {0.f, 0.f};

    unsigned int u0[4], u1[4];
#pragma unroll
    for (int k = 0; k < 4; ++k)
        u0[k] = xlp[(size_t)col_idx[min(beg + k, end - 1)] * 64 + lane];
#pragma unroll
    for (int k = 0; k < 4; ++k)
        u1[k] = xlp[(size_t)col_idx[min(beg + 4 + k, end - 1)] * 64 + lane];

    int idx = beg;
    auto process4 = [&](unsigned int (&buf)[4]) {
        v2f x0 = bfpair_to_v2(buf[0]);
        v2f x1 = bfpair_to_v2(buf[1]);
        v2f x2 = bfpair_to_v2(buf[2]);
        v2f x3 = bfpair_to_v2(buf[3]);
#pragma unroll
        for (int k = 0; k < 4; ++k) {                 // prefetch at distance 8 (clamped)
            int nx = min(idx + 8 + k, end - 1);
            buf[k] = xlp[(size_t)col_idx[nx] * 64 + lane];
        }
        v2f p0 = x0 + xr_v;                           // v_pk_add_f32
        v2f p1 = x1 + xr_v;
        v2f p2 = x2 + xr_v;
        v2f p3 = x3 + xr_v;
        p0 = __builtin_elementwise_max(p0, p0 * SLOPE);   // pk_mul + pk_max
        p1 = __builtin_elementwise_max(p1, p1 * SLOPE);
        p2 = __builtin_elementwise_max(p2, p2 * SLOPE);
        p3 = __builtin_elementwise_max(p3, p3 * SLOPE);
        float s0 = fmaf(p0.x, a2.x, p0.y * a2.y);     // horizontal dot (scalar)
        float s1 = fmaf(p1.x, a2.x, p1.y * a2.y);
        float s2 = fmaf(p2.x, a2.x, p2.y * a2.y);
        float s3 = fmaf(p3.x, a2.x, p3.y * a2.y);
        s0 += __shfl_xor(s0, 1); s1 += __shfl_xor(s1, 1);
        s2 += __shfl_xor(s2, 1); s3 += __shfl_xor(s3, 1);
        s0 += __shfl_xor(s0, 2); s1 += __shfl_xor(s1, 2);
        s2 += __shfl_xor(s2, 2); s3 += __shfl_xor(s3, 2);
        s0 += __shfl_xor(s0, 4); s1 += __shfl_xor(s1, 4);
        s2 += __shfl_xor(s2, 4); s3 += __shfl_xor(s3, 4);
        s0 += __shfl_xor(s0, 8); s1 += __shfl_xor(s1, 8);
        s2 += __shfl_xor(s2, 8); s3 += __shfl_xor(s3, 8);
        float w0 = fast_exp2(s0);
        float w1 = fast_exp2(s1);
        float w2 = fast_exp2(s2);
        float w3 = fast_exp2(s3);
        l0 += w0 + w1;
        l1 += w2 + w3;
        acc0 = x0 * w0 + acc0;                        // v_pk_fma_f32 (contracted)
        acc0 = x1 * w1 + acc0;
        acc1 = x2 * w2 + acc1;
        acc1 = x3 * w3 + acc1;
    };

    while (idx + 3 < end) {
        process4(u0);
        idx += 4;
        if (idx + 3 >= end) break;
        process4(u1);
        idx += 4;
    }
    for (; idx < end; ++idx) {                        // tail <=3 edges: reload (L2-warm)
        v2f xa = bfpair_to_v2(xlp[(size_t)col_idx[idx] * 64 + lane]);
        v2f pa = xa + xr_v;
        pa = __builtin_elementwise_max(pa, pa * SLOPE);
        float sa = fmaf(pa.x, a2.x, pa.y * a2.y);
        sa += __shfl_xor(sa, 1);
        sa += __shfl_xor(sa, 2);
        sa += __shfl_xor(sa, 4);
        sa += __shfl_xor(sa, 8);
        float wa = fast_exp2(sa);
        l0 += wa;
        acc0 = xa * wa + acc0;
    }
    float rl = 1.f / (l0 + l1);
    size_t o = (size_t)v * 64 + lane;
    float2 yv = ((const float2*)y)[o];
    v2f at = acc0 + acc1;
    yv.x = fmaf(at.x, rl, yv.x);                      // agg + res(+bias)
    yv.y = fmaf(at.y, rl, yv.y);
    ((float2*)y)[o] = yv;
}

// ---------- BatchNorm stats: coalesced float4, LDS reduce, atomics ----------
__global__ __launch_bounds__(256) void bn_stats_kernel(const float* __restrict__ y,
                                                       float* __restrict__ sums) {
    __shared__ float ls[256][4];
    __shared__ float ls2[256][4];
    int t = threadIdx.x;
    float4 s = make_float4(0.f, 0.f, 0.f, 0.f);
    float4 s2 = make_float4(0.f, 0.f, 0.f, 0.f);
    const float4* y4 = (const float4*)y;
    for (int i = blockIdx.x * 256 + t; i < N * D / 4; i += gridDim.x * 256) {
        float4 v = y4[i];                             // cols 4*(t&31)..+3 (fixed)
        s.x += v.x; s.y += v.y; s.z += v.z; s.w += v.w;
        s2.x = fmaf(v.x, v.x, s2.x); s2.y = fmaf(v.y, v.y, s2.y);
        s2.z = fmaf(v.z, v.z, s2.z); s2.w = fmaf(v.w, v.w, s2.w);
    }
    ls[t][0] = s.x;  ls[t][1] = s.y;  ls[t][2] = s.z;  ls[t][3] = s.w;
    ls2[t][0] = s2.x; ls2[t][1] = s2.y; ls2[t][2] = s2.z; ls2[t][3] = s2.w;
    __syncthreads();
    if (t < D) {
        int g = t >> 2, e = t & 3;
        float a = 0.f, b = 0.f;
#pragma unroll
        for (int j = 0; j < 8; ++j) {
            a += ls[g + 32 * j][e];
            b += ls2[g + 32 * j][e];
        }
        atomicAdd(&sums[t], a);
        atomicAdd(&sums[D + t], b);
    }
}

extern "C" void kernel_launch(void* const* d_in, const int* in_sizes, int n_in,
                              void* d_out, int out_size, void* d_ws, size_t ws_size,
                              hipStream_t stream) {
    const float* x_in  = (const float*)d_in[0];
    const int*   ei    = (const int*)d_in[1];
    const float* Wl    = (const float*)d_in[2];
    const float* Wr    = (const float*)d_in[3];
    const float* att   = (const float*)d_in[4];
    const float* bias  = (const float*)d_in[5];
    const float* Wres  = (const float*)d_in[6];
    const float* gamma = (const float*)d_in[7];
    const float* beta  = (const float*)d_in[8];
    const float* Wout  = (const float*)d_in[9];
    const float* bout  = (const float*)d_in[10];
    float* out = (float*)d_out;

    char* ws = (char*)d_ws;
    size_t off = 0;
    auto alloc = [&](size_t bytes) {
        void* p = ws + off;
        off = (off + bytes + 255) & ~(size_t)255;
        return p;
    };
    hbf*   xl       = (hbf*)alloc((size_t)N * D * sizeof(hbf));
    hbf*   xr       = (hbf*)alloc((size_t)N * D * sizeof(hbf));
    float* y        = (float*)alloc((size_t)N * D * sizeof(float));
    hbf*   Wph      = (hbf*)alloc((size_t)10 * D * D * sizeof(hbf));
    int*   row_ptr  = (int*)alloc((size_t)(N + 1) * sizeof(int));
    int*   col_idx  = (int*)alloc((size_t)E2 * sizeof(int));
    int*   counts   = (int*)alloc((size_t)N * sizeof(int));   // reused as write ptr
    int*   blk_sums = (int*)alloc(128 * sizeof(int));
    float* sums     = (float*)alloc(3 * 2 * D * sizeof(float));  // per-layer bn sums

    const int NB = (N + 511) / 512;                  // 98 scan blocks

    // CSR build + weight packing (+ one upfront zero of all 3 bn-sum buffers)
    (void)hipMemsetAsync(counts, 0, (size_t)N * sizeof(int), stream);
    (void)hipMemsetAsync(sums, 0, 3 * 2 * D * sizeof(float), stream);
    count_kernel<<<(E2 + 255) / 256, 256, 0, stream>>>(ei, counts);
    pack_w_kernel<<<10 * 16384 / 256, 256, 0, stream>>>(Wl, Wr, Wres, Wout, Wph);
    scan_block_kernel<<<NB, 512, 0, stream>>>(counts, row_ptr, blk_sums);
    scan_sums_kernel<<<1, 128, 0, stream>>>(blk_sums, NB);
    scan_add_kernel<<<(N + 255) / 256, 256, 0, stream>>>(row_ptr, blk_sums);
    (void)hipMemsetAsync(counts, 0, (size_t)N * sizeof(int), stream);
    scatter_kernel<<<(E2 + 255) / 256, 256, 0, stream>>>(ei, row_ptr, counts, col_idx);

    for (int i = 0; i < L; ++i) {
        const float* xin = (i == 0) ? x_in : y;      // in-place (tile snapshot) for 1,2
        const float* sm  = (i == 0) ? nullptr : sums + (size_t)(i - 1) * 2 * D;
        const float* ga  = (i == 0) ? nullptr : gamma + (size_t)(i - 1) * D;
        const float* be  = (i == 0) ? nullptr : beta + (size_t)(i - 1) * D;
        gemm3_mfma_kernel<<<TILES, 256, 0, stream>>>(xin, sm, ga, be, Wph,
                                                     i, 3 + i, 6 + i,
                                                     bias + (size_t)i * D, xl, xr, y);
        gat_kernel<<<N / 4, 256, 0, stream>>>(xl, xr, y, row_ptr, col_idx,
                                              att + (size_t)i * H * C);
        bn_stats_kernel<<<512, 256, 0, stream>>>(y, sums + (size_t)i * 2 * D);
    }

    gemm_out_mfma_kernel<<<TILES, 256, 0, stream>>>(y, sums + (size_t)2 * 2 * D,
                                                    gamma + (size_t)2 * D,
                                                    beta + (size_t)2 * D, Wph, bout, out);
}

// Round 14
// 489.809 us; speedup vs baseline: 1.4829x; 1.0164x over previous
//
#include <hip/hip_runtime.h>
#include <hip/hip_bf16.h>

constexpr int N = 50000;
constexpr int E = 800000;
constexpr int D = 128;
constexpr int H = 4;
constexpr int C = 32;
constexpr int L = 3;
constexpr int E2 = E + N;           // edges + self loops
constexpr float SLOPE = 0.2f;
constexpr float BN_EPS = 1e-5f;
constexpr float LOG2E = 1.4426950408889634f;
constexpr int TILES = (N + 63) / 64;                 // 782 row tiles

typedef __attribute__((ext_vector_type(8))) short bf16x8_t;   // 8 bf16 (4 VGPRs)
typedef __attribute__((ext_vector_type(4))) float f32x4_t;    // MFMA C/D
typedef __attribute__((ext_vector_type(2))) float v2f;        // packed fp32 (v_pk_*)

using hbf = __hip_bfloat16;

__device__ __forceinline__ float fast_exp2(float x) { return __builtin_amdgcn_exp2f(x); }

__device__ __forceinline__ short f2bf(float v) {
    hbf h = __float2bfloat16(v);
    return *reinterpret_cast<short*>(&h);
}
__device__ __forceinline__ v2f bfpair_to_v2(unsigned int u) {
    v2f r;
    r.x = __uint_as_float(u << 16);
    r.y = __uint_as_float(u & 0xffff0000u);
    return r;
}

// ---------- CSR build ----------
__global__ void count_kernel(const int* __restrict__ ei, int* __restrict__ counts) {
    int i = blockIdx.x * blockDim.x + threadIdx.x;
    if (i >= E2) return;
    int dst = (i < E) ? ei[E + i] : (i - E);
    atomicAdd(&counts[dst], 1);
}

__global__ __launch_bounds__(512) void scan_block_kernel(const int* __restrict__ counts,
                                                         int* __restrict__ row_ptr,
                                                         int* __restrict__ blk_sums) {
    __shared__ int s[512];
    int t = threadIdx.x;
    int i = blockIdx.x * 512 + t;
    int v = (i < N) ? counts[i] : 0;
    s[t] = v;
    __syncthreads();
    for (int off = 1; off < 512; off <<= 1) {
        int add = (t >= off) ? s[t - off] : 0;
        __syncthreads();
        s[t] += add;
        __syncthreads();
    }
    if (i < N) row_ptr[i] = s[t] - v;                 // exclusive within block
    if (t == 511) blk_sums[blockIdx.x] = s[511];
}

__global__ __launch_bounds__(128) void scan_sums_kernel(int* __restrict__ blk, int nb) {
    __shared__ int s[128];
    int t = threadIdx.x;
    int v = (t < nb) ? blk[t] : 0;
    s[t] = v;
    __syncthreads();
    for (int off = 1; off < 128; off <<= 1) {
        int add = (t >= off) ? s[t - off] : 0;
        __syncthreads();
        s[t] += add;
        __syncthreads();
    }
    if (t < nb) blk[t] = s[t] - v;                    // exclusive block offsets
}

__global__ void scan_add_kernel(int* __restrict__ row_ptr, const int* __restrict__ blk) {
    int i = blockIdx.x * blockDim.x + threadIdx.x;
    if (i < N) row_ptr[i] += blk[i >> 9];
    if (i == 0) row_ptr[N] = E2;
}

__global__ void scatter_kernel(const int* __restrict__ ei, const int* __restrict__ row_ptr,
                               int* __restrict__ wp, int* __restrict__ col_idx) {
    int i = blockIdx.x * blockDim.x + threadIdx.x;
    if (i >= E2) return;
    int src, dst;
    if (i < E) { src = ei[i]; dst = ei[E + i]; }
    else       { src = i - E; dst = i - E; }
    int pos = row_ptr[dst] + atomicAdd(&wp[dst], 1);
    col_idx[pos] = src;
}

// ---------- pack 10 weight matrices into MFMA B-fragment order (hi bf16 only) ----------
// B frag for 16x16x32: lane holds B[k = ks*32 + (lane>>4)*8 + j][n = nb*16 + (lane&15)],
// j=0..7. Packed index: (mat*2048 + (ks*8+nb)*64 + lane)*8 + j  -> lane-contiguous 16B.
__global__ __launch_bounds__(256) void pack_w_kernel(
        const float* __restrict__ Wl, const float* __restrict__ Wr,
        const float* __restrict__ Wres, const float* __restrict__ Wout,
        hbf* __restrict__ Wph) {
    int gid = blockIdx.x * 256 + threadIdx.x;        // 10 * 16384
    int mat = gid >> 14;
    int d = gid & 16383;
    const float* W;
    if (mat < 3)      W = Wl + (size_t)mat * 16384;
    else if (mat < 6) W = Wr + (size_t)(mat - 3) * 16384;
    else if (mat < 9) W = Wres + (size_t)(mat - 6) * 16384;
    else              W = Wout;
    int j = d & 7, lane = (d >> 3) & 63, nb = (d >> 9) & 7, ks = d >> 12;
    int k = ks * 32 + ((lane >> 4) * 8) + j;
    int n = nb * 16 + (lane & 15);
    Wph[gid] = __float2bfloat16(W[k * D + n]);
}

// ---------- fused 3-matrix MFMA GEMM, one 64-row tile per block ----------
// X = leaky(bn(x)) if sums else x; bn scale/shift derived in-block from sums+gamma+beta.
// xl = bf16(X@Wl), xr = bf16(X@Wr), y = X@Wres + bias.  In-place-safe (x == y): tile
// snapshot into LDS before any store; each tile owned by one block.
// Wave w owns n-blocks {2w, 2w+1}; B frags (24) in VGPRs, loaded once per block.
// 2-term split: X@W ~= Xh@Wh + Xl@Wh (W bf16-rounded).
__global__ __launch_bounds__(256) void gemm3_mfma_kernel(
        const float* x, const float* __restrict__ sums,
        const float* __restrict__ gamma, const float* __restrict__ beta,
        const hbf* __restrict__ Wph,
        int mL, int mR, int mS, const float* __restrict__ bias,
        hbf* __restrict__ xl, hbf* __restrict__ xr, float* y) {
    __shared__ float xs[64][133];                     // +5 pad: 2-way max bank aliasing
    __shared__ float ssl[2][128];                     // bn scale/shift
    int t = threadIdx.x;
    int wave = t >> 6;
    int lane = t & 63;
    int nb0 = wave * 2;                               // this wave's two n-blocks
    int row0 = blockIdx.x * 64;

    if (sums && t < 128) {                            // fold of old bn_finalize
        float mean = sums[t] * (1.0f / N);
        float var = fmaxf(sums[D + t] * (1.0f / N) - mean * mean, 0.f);
        float sc = gamma[t] * rsqrtf(var + BN_EPS);
        ssl[0][t] = sc;
        ssl[1][t] = beta[t] - mean * sc;
    }

    const bf16x8_t* B = (const bf16x8_t*)Wph;
    bf16x8_t bL[4][2], bR[4][2], bS[4][2];            // 24 frags = 96 VGPRs, loaded once
#pragma unroll
    for (int ks = 0; ks < 4; ++ks)
#pragma unroll
        for (int j = 0; j < 2; ++j) {
            int bo = (ks * 8 + nb0 + j) * 64 + lane;
            bL[ks][j] = B[mL * 2048 + bo];
            bR[ks][j] = B[mR * 2048 + bo];
            bS[ks][j] = B[mS * 2048 + bo];
        }
    __syncthreads();                                  // ssl visible

    int cg = (t & 31) * 4;                            // staging col group
    {
        float sc_[4] = {1.f, 1.f, 1.f, 1.f}, sh_[4] = {0.f, 0.f, 0.f, 0.f};
        if (sums) {
#pragma unroll
            for (int j = 0; j < 4; ++j) { sc_[j] = ssl[0][cg + j]; sh_[j] = ssl[1][cg + j]; }
        }
        const float4* x4 = (const float4*)(x + (size_t)row0 * D);
        for (int i = t; i < 64 * 32; i += 256) {
            int r = i >> 5;
            float4 v = make_float4(0.f, 0.f, 0.f, 0.f);
            if (row0 + r < N) {
                v = x4[i];
                if (sums) {
                    v.x = fmaf(v.x, sc_[0], sh_[0]); v.x = fmaxf(v.x, SLOPE * v.x);
                    v.y = fmaf(v.y, sc_[1], sh_[1]); v.y = fmaxf(v.y, SLOPE * v.y);
                    v.z = fmaf(v.z, sc_[2], sh_[2]); v.z = fmaxf(v.z, SLOPE * v.z);
                    v.w = fmaf(v.w, sc_[3], sh_[3]); v.w = fmaxf(v.w, SLOPE * v.w);
                }
            }
            *(float4*)&xs[r][cg] = v;
        }
    }
    __syncthreads();

    int col = lane & 15;
    int koff = (lane >> 4) * 8;
    for (int mm = 0; mm < 4; ++mm) {
        int mrow = mm * 16 + (lane & 15);
        f32x4_t aL[2], aR[2], aS[2];
#pragma unroll
        for (int j = 0; j < 2; ++j) {
            aL[j] = (f32x4_t)0.f; aR[j] = (f32x4_t)0.f; aS[j] = (f32x4_t)0.f;
        }
#pragma unroll
        for (int ks = 0; ks < 4; ++ks) {
            const float* src = &xs[mrow][ks * 32 + koff];
            float4 f0 = *(const float4*)src;
            float4 f1 = *(const float4*)(src + 4);
            float f[8] = {f0.x, f0.y, f0.z, f0.w, f1.x, f1.y, f1.z, f1.w};
            bf16x8_t ah, al;
#pragma unroll
            for (int j = 0; j < 8; ++j) {
                short hi = f2bf(f[j]);
                unsigned int hu = ((unsigned int)(unsigned short)hi) << 16;
                ah[j] = hi;
                al[j] = f2bf(f[j] - __uint_as_float(hu));
            }
#pragma unroll
            for (int j = 0; j < 2; ++j) {
                aL[j] = __builtin_amdgcn_mfma_f32_16x16x32_bf16(ah, bL[ks][j], aL[j], 0, 0, 0);
                aL[j] = __builtin_amdgcn_mfma_f32_16x16x32_bf16(al, bL[ks][j], aL[j], 0, 0, 0);
                aR[j] = __builtin_amdgcn_mfma_f32_16x16x32_bf16(ah, bR[ks][j], aR[j], 0, 0, 0);
                aR[j] = __builtin_amdgcn_mfma_f32_16x16x32_bf16(al, bR[ks][j], aR[j], 0, 0, 0);
                aS[j] = __builtin_amdgcn_mfma_f32_16x16x32_bf16(ah, bS[ks][j], aS[j], 0, 0, 0);
                aS[j] = __builtin_amdgcn_mfma_f32_16x16x32_bf16(al, bS[ks][j], aS[j], 0, 0, 0);
            }
        }
        // C/D layout: col = lane&15, row = (lane>>4)*4 + r
        int rowq = row0 + mm * 16 + (lane >> 4) * 4;
#pragma unroll
        for (int j = 0; j < 2; ++j) {
            int n = (nb0 + j) * 16 + col;
            float bv = bias[n];
#pragma unroll
            for (int r = 0; r < 4; ++r) {
                int row = rowq + r;
                if (row < N) {
                    xl[(size_t)row * D + n] = __float2bfloat16(aL[j][r]);
                    xr[(size_t)row * D + n] = __float2bfloat16(aR[j][r]);
                    y[(size_t)row * D + n]  = aS[j][r] + bv;
                }
            }
        }
    }
}

// ---------- final linear via MFMA, same structure (BN+leaky on load) ----------
__global__ __launch_bounds__(256) void gemm_out_mfma_kernel(
        const float* __restrict__ x, const float* __restrict__ sums,
        const float* __restrict__ gamma, const float* __restrict__ beta,
        const hbf* __restrict__ Wph, const float* __restrict__ b,
        float* __restrict__ out) {
    __shared__ float xs[64][133];
    __shared__ float ssl[2][128];
    int t = threadIdx.x;
    int wave = t >> 6;
    int lane = t & 63;
    int nb0 = wave * 2;
    int row0 = blockIdx.x * 64;

    if (t < 128) {
        float mean = sums[t] * (1.0f / N);
        float var = fmaxf(sums[D + t] * (1.0f / N) - mean * mean, 0.f);
        float sc = gamma[t] * rsqrtf(var + BN_EPS);
        ssl[0][t] = sc;
        ssl[1][t] = beta[t] - mean * sc;
    }

    const bf16x8_t* B = (const bf16x8_t*)Wph + 9 * 2048;      // matrix 9 = Wout
    bf16x8_t bW[4][2];
#pragma unroll
    for (int ks = 0; ks < 4; ++ks)
#pragma unroll
        for (int j = 0; j < 2; ++j)
            bW[ks][j] = B[(ks * 8 + nb0 + j) * 64 + lane];
    __syncthreads();

    int cg = (t & 31) * 4;
    {
        float sc_[4], sh_[4];
#pragma unroll
        for (int j = 0; j < 4; ++j) { sc_[j] = ssl[0][cg + j]; sh_[j] = ssl[1][cg + j]; }
        const float4* x4 = (const float4*)(x + (size_t)row0 * D);
        for (int i = t; i < 64 * 32; i += 256) {
            int r = i >> 5;
            float4 v = make_float4(0.f, 0.f, 0.f, 0.f);
            if (row0 + r < N) {
                v = x4[i];
                v.x = fmaf(v.x, sc_[0], sh_[0]); v.x = fmaxf(v.x, SLOPE * v.x);
                v.y = fmaf(v.y, sc_[1], sh_[1]); v.y = fmaxf(v.y, SLOPE * v.y);
                v.z = fmaf(v.z, sc_[2], sh_[2]); v.z = fmaxf(v.z, SLOPE * v.z);
                v.w = fmaf(v.w, sc_[3], sh_[3]); v.w = fmaxf(v.w, SLOPE * v.w);
            }
            *(float4*)&xs[r][cg] = v;
        }
    }
    __syncthreads();

    int col = lane & 15;
    int koff = (lane >> 4) * 8;
    for (int mm = 0; mm < 4; ++mm) {
        int mrow = mm * 16 + (lane & 15);
        f32x4_t acc[2];
        acc[0] = (f32x4_t)0.f; acc[1] = (f32x4_t)0.f;
#pragma unroll
        for (int ks = 0; ks < 4; ++ks) {
            const float* src = &xs[mrow][ks * 32 + koff];
            float4 f0 = *(const float4*)src;
            float4 f1 = *(const float4*)(src + 4);
            float f[8] = {f0.x, f0.y, f0.z, f0.w, f1.x, f1.y, f1.z, f1.w};
            bf16x8_t ah, al;
#pragma unroll
            for (int j = 0; j < 8; ++j) {
                short hi = f2bf(f[j]);
                unsigned int hu = ((unsigned int)(unsigned short)hi) << 16;
                ah[j] = hi;
                al[j] = f2bf(f[j] - __uint_as_float(hu));
            }
#pragma unroll
            for (int j = 0; j < 2; ++j) {
                acc[j] = __builtin_amdgcn_mfma_f32_16x16x32_bf16(ah, bW[ks][j], acc[j], 0, 0, 0);
                acc[j] = __builtin_amdgcn_mfma_f32_16x16x32_bf16(al, bW[ks][j], acc[j], 0, 0, 0);
            }
        }
        int rowq = row0 + mm * 16 + (lane >> 4) * 4;
#pragma unroll
        for (int j = 0; j < 2; ++j) {
            int n = (nb0 + j) * 16 + col;
            float bv = b[n];
#pragma unroll
            for (int r = 0; r < 4; ++r) {
                int row = rowq + r;
                if (row < N) out[(size_t)row * D + n] = acc[j][r] + bv;
            }
        }
    }
}

// ---------- GATv2 aggregation: wave/node, TWO EDGES PER WAVE ----------
// Lane covers 4 channels (sublane=lane&31 -> ch 4s..4s+3); half=lane>>5 picks the
// edge of a pair. Head = 8 sublanes -> shuffle tree is 3 levels (was 4), and all
// elementwise ops cover 2 edges per instruction (~14 vs ~23 wave-instr/edge).
// Cross-half combine of (l, acc) once at the end via shfl_xor(.,32); tail edges
// zero half 1's weight. No online max (scores BN-bounded). Fixed-size buffers with
// literal indices only (r10: dynamic indexing demotes to LDS). log2-domain scores.
__global__ __launch_bounds__(256) void gat_kernel(
        const hbf* __restrict__ xl, const hbf* __restrict__ xr,
        float* y, const int* __restrict__ row_ptr,
        const int* __restrict__ col_idx, const float* __restrict__ att) {
    int wave = threadIdx.x >> 6;
    int lane = threadIdx.x & 63;
    int half = lane >> 5;                             // which edge of the pair
    int sub  = lane & 31;                             // channels 4*sub .. 4*sub+3
    int v = blockIdx.x * 4 + wave;
    const uint2* xlp = (const uint2*)xl;              // 4 bf16 per lane
    const uint2* xrp = (const uint2*)xr;
    uint2 xru = xrp[(size_t)v * 32 + sub];
    v2f xr_a = bfpair_to_v2(xru.x);
    v2f xr_b = bfpair_to_v2(xru.y);
    float4 a4 = ((const float4*)att)[sub];            // head = sub/8
    v2f a_a; a_a.x = a4.x * LOG2E; a_a.y = a4.y * LOG2E;
    v2f a_b; a_b.x = a4.z * LOG2E; a_b.y = a4.w * LOG2E;
    int beg = row_ptr[v], end = row_ptr[v + 1];
    float l = 0.f;
    v2f acc_a = {0.f, 0.f};
    v2f acc_b = {0.f, 0.f};

    // group = 2 pairs = 4 edges; pair p covers edges idx+2p+half
    uint2 u0[2], u1[2];
    u0[0] = xlp[(size_t)col_idx[min(beg + 0 + half, end - 1)] * 32 + sub];
    u0[1] = xlp[(size_t)col_idx[min(beg + 2 + half, end - 1)] * 32 + sub];
    u1[0] = xlp[(size_t)col_idx[min(beg + 4 + half, end - 1)] * 32 + sub];
    u1[1] = xlp[(size_t)col_idx[min(beg + 6 + half, end - 1)] * 32 + sub];

    int idx = beg;
    auto process4 = [&](uint2 (&buf)[2]) {
        v2f xa0 = bfpair_to_v2(buf[0].x);
        v2f xb0 = bfpair_to_v2(buf[0].y);
        v2f xa1 = bfpair_to_v2(buf[1].x);
        v2f xb1 = bfpair_to_v2(buf[1].y);
        // prefetch at distance 8 (clamped; over-prefetch never consumed)
        buf[0] = xlp[(size_t)col_idx[min(idx + 8 + half, end - 1)] * 32 + sub];
        buf[1] = xlp[(size_t)col_idx[min(idx + 10 + half, end - 1)] * 32 + sub];

        v2f pa0 = xa0 + xr_a, pb0 = xb0 + xr_b;       // v_pk_add_f32
        v2f pa1 = xa1 + xr_a, pb1 = xb1 + xr_b;
        pa0 = __builtin_elementwise_max(pa0, pa0 * SLOPE);
        pb0 = __builtin_elementwise_max(pb0, pb0 * SLOPE);
        pa1 = __builtin_elementwise_max(pa1, pa1 * SLOPE);
        pb1 = __builtin_elementwise_max(pb1, pb1 * SLOPE);
        v2f t0 = pa0 * a_a; t0 = pb0 * a_b + t0;      // pk_mul + pk_fma
        v2f t1 = pa1 * a_a; t1 = pb1 * a_b + t1;
        float s0 = t0.x + t0.y;
        float s1 = t1.x + t1.y;
        s0 += __shfl_xor(s0, 1);  s1 += __shfl_xor(s1, 1);
        s0 += __shfl_xor(s0, 2);  s1 += __shfl_xor(s1, 2);
        s0 += __shfl_xor(s0, 4);  s1 += __shfl_xor(s1, 4);
        float w0 = fast_exp2(s0);
        float w1 = fast_exp2(s1);
        l += w0 + w1;
        acc_a = xa0 * w0 + acc_a;                     // v_pk_fma_f32
        acc_b = xb0 * w0 + acc_b;
        acc_a = xa1 * w1 + acc_a;
        acc_b = xb1 * w1 + acc_b;
    };

    while (idx + 3 < end) {
        process4(u0);
        idx += 4;
        if (idx + 3 >= end) break;
        process4(u1);
        idx += 4;
    }
    for (; idx < end; ++idx) {                        // tail <=3: both halves same edge
        uint2 xu = xlp[(size_t)col_idx[idx] * 32 + sub];
        v2f xa = bfpair_to_v2(xu.x);
        v2f xb = bfpair_to_v2(xu.y);
        v2f pa = xa + xr_a, pb = xb + xr_b;
        pa = __builtin_elementwise_max(pa, pa * SLOPE);
        pb = __builtin_elementwise_max(pb, pb * SLOPE);
        v2f tt = pa * a_a; tt = pb * a_b + tt;
        float sa = tt.x + tt.y;
        sa += __shfl_xor(sa, 1);
        sa += __shfl_xor(sa, 2);
        sa += __shfl_xor(sa, 4);
        float wa = half ? 0.f : fast_exp2(sa);        // avoid double count
        l += wa;
        acc_a = xa * wa + acc_a;
        acc_b = xb * wa + acc_b;
    }
    // combine the two halves (each held one edge of every pair)
    l += __shfl_xor(l, 32);
    acc_a.x += __shfl_xor(acc_a.x, 32);
    acc_a.y += __shfl_xor(acc_a.y, 32);
    acc_b.x += __shfl_xor(acc_b.x, 32);
    acc_b.y += __shfl_xor(acc_b.y, 32);
    if (half == 0) {
        float rl = 1.f / l;
        size_t o = (size_t)v * 32 + sub;
        float4 yv = ((const float4*)y)[o];
        yv.x = fmaf(acc_a.x, rl, yv.x);               // agg + res(+bias)
        yv.y = fmaf(acc_a.y, rl, yv.y);
        yv.z = fmaf(acc_b.x, rl, yv.z);
        yv.w = fmaf(acc_b.y, rl, yv.w);
        ((float4*)y)[o] = yv;
    }
}

// ---------- BatchNorm stats: coalesced float4, LDS reduce, atomics ----------
__global__ __launch_bounds__(256) void bn_stats_kernel(const float* __restrict__ y,
                                                       float* __restrict__ sums) {
    __shared__ float ls[256][4];
    __shared__ float ls2[256][4];
    int t = threadIdx.x;
    float4 s = make_float4(0.f, 0.f, 0.f, 0.f);
    float4 s2 = make_float4(0.f, 0.f, 0.f, 0.f);
    const float4* y4 = (const float4*)y;
    for (int i = blockIdx.x * 256 + t; i < N * D / 4; i += gridDim.x * 256) {
        float4 v = y4[i];                             // cols 4*(t&31)..+3 (fixed)
        s.x += v.x; s.y += v.y; s.z += v.z; s.w += v.w;
        s2.x = fmaf(v.x, v.x, s2.x); s2.y = fmaf(v.y, v.y, s2.y);
        s2.z = fmaf(v.z, v.z, s2.z); s2.w = fmaf(v.w, v.w, s2.w);
    }
    ls[t][0] = s.x;  ls[t][1] = s.y;  ls[t][2] = s.z;  ls[t][3] = s.w;
    ls2[t][0] = s2.x; ls2[t][1] = s2.y; ls2[t][2] = s2.z; ls2[t][3] = s2.w;
    __syncthreads();
    if (t < D) {
        int g = t >> 2, e = t & 3;
        float a = 0.f, b = 0.f;
#pragma unroll
        for (int j = 0; j < 8; ++j) {
            a += ls[g + 32 * j][e];
            b += ls2[g + 32 * j][e];
        }
        atomicAdd(&sums[t], a);
        atomicAdd(&sums[D + t], b);
    }
}

extern "C" void kernel_launch(void* const* d_in, const int* in_sizes, int n_in,
                              void* d_out, int out_size, void* d_ws, size_t ws_size,
                              hipStream_t stream) {
    const float* x_in  = (const float*)d_in[0];
    const int*   ei    = (const int*)d_in[1];
    const float* Wl    = (const float*)d_in[2];
    const float* Wr    = (const float*)d_in[3];
    const float* att   = (const float*)d_in[4];
    const float* bias  = (const float*)d_in[5];
    const float* Wres  = (const float*)d_in[6];
    const float* gamma = (const float*)d_in[7];
    const float* beta  = (const float*)d_in[8];
    const float* Wout  = (const float*)d_in[9];
    const float* bout  = (const float*)d_in[10];
    float* out = (float*)d_out;

    char* ws = (char*)d_ws;
    size_t off = 0;
    auto alloc = [&](size_t bytes) {
        void* p = ws + off;
        off = (off + bytes + 255) & ~(size_t)255;
        return p;
    };
    hbf*   xl       = (hbf*)alloc((size_t)N * D * sizeof(hbf));
    hbf*   xr       = (hbf*)alloc((size_t)N * D * sizeof(hbf));
    float* y        = (float*)alloc((size_t)N * D * sizeof(float));
    hbf*   Wph      = (hbf*)alloc((size_t)10 * D * D * sizeof(hbf));
    int*   row_ptr  = (int*)alloc((size_t)(N + 1) * sizeof(int));
    int*   col_idx  = (int*)alloc((size_t)E2 * sizeof(int));
    int*   counts   = (int*)alloc((size_t)N * sizeof(int));   // reused as write ptr
    int*   blk_sums = (int*)alloc(128 * sizeof(int));
    float* sums     = (float*)alloc(3 * 2 * D * sizeof(float));  // per-layer bn sums

    const int NB = (N + 511) / 512;                  // 98 scan blocks

    // CSR build + weight packing (+ one upfront zero of all 3 bn-sum buffers)
    (void)hipMemsetAsync(counts, 0, (size_t)N * sizeof(int), stream);
    (void)hipMemsetAsync(sums, 0, 3 * 2 * D * sizeof(float), stream);
    count_kernel<<<(E2 + 255) / 256, 256, 0, stream>>>(ei, counts);
    pack_w_kernel<<<10 * 16384 / 256, 256, 0, stream>>>(Wl, Wr, Wres, Wout, Wph);
    scan_block_kernel<<<NB, 512, 0, stream>>>(counts, row_ptr, blk_sums);
    scan_sums_kernel<<<1, 128, 0, stream>>>(blk_sums, NB);
    scan_add_kernel<<<(N + 255) / 256, 256, 0, stream>>>(row_ptr, blk_sums);
    (void)hipMemsetAsync(counts, 0, (size_t)N * sizeof(int), stream);
    scatter_kernel<<<(E2 + 255) / 256, 256, 0, stream>>>(ei, row_ptr, counts, col_idx);

    for (int i = 0; i < L; ++i) {
        const float* xin = (i == 0) ? x_in : y;      // in-place (tile snapshot) for 1,2
        const float* sm  = (i == 0) ? nullptr : sums + (size_t)(i - 1) * 2 * D;
        const float* ga  = (i == 0) ? nullptr : gamma + (size_t)(i - 1) * D;
        const float* be  = (i == 0) ? nullptr : beta + (size_t)(i - 1) * D;
        gemm3_mfma_kernel<<<TILES, 256, 0, stream>>>(xin, sm, ga, be, Wph,
                                                     i, 3 + i, 6 + i,
                                                     bias + (size_t)i * D, xl, xr, y);
        gat_kernel<<<N / 4, 256, 0, stream>>>(xl, xr, y, row_ptr, col_idx,
                                              att + (size_t)i * H * C);
        bn_stats_kernel<<<512, 256, 0, stream>>>(y, sums + (size_t)i * 2 * D);
    }

    gemm_out_mfma_kernel<<<TILES, 256, 0, stream>>>(y, sums + (size_t)2 * 2 * D,
                                                    gamma + (size_t)2 * D,
                                                    beta + (size_t)2 * D, Wph, bout, out);
}

// Round 15
// 482.184 us; speedup vs baseline: 1.5063x; 1.0158x over previous
//
#include <hip/hip_runtime.h>
#include <hip/hip_bf16.h>

constexpr int N = 50000;
constexpr int E = 800000;
constexpr int D = 128;
constexpr int H = 4;
constexpr int C = 32;
constexpr int L = 3;
constexpr int E2 = E + N;           // edges + self loops
constexpr float SLOPE = 0.2f;
constexpr float BN_EPS = 1e-5f;
constexpr float LOG2E = 1.4426950408889634f;
constexpr int TILES = (N + 63) / 64;                 // 782 row tiles

typedef __attribute__((ext_vector_type(8))) short bf16x8_t;   // 8 bf16 (4 VGPRs)
typedef __attribute__((ext_vector_type(4))) float f32x4_t;    // MFMA C/D
typedef __attribute__((ext_vector_type(2))) float v2f;        // packed fp32 (v_pk_*)

using hbf = __hip_bfloat16;

__device__ __forceinline__ float fast_exp2(float x) { return __builtin_amdgcn_exp2f(x); }

__device__ __forceinline__ short f2bf(float v) {
    hbf h = __float2bfloat16(v);
    return *reinterpret_cast<short*>(&h);
}
__device__ __forceinline__ v2f bfpair_to_v2(unsigned int u) {
    v2f r;
    r.x = __uint_as_float(u << 16);
    r.y = __uint_as_float(u & 0xffff0000u);
    return r;
}

// ---------- CSR build ----------
__global__ void count_kernel(const int* __restrict__ ei, int* __restrict__ counts) {
    int i = blockIdx.x * blockDim.x + threadIdx.x;
    if (i >= E2) return;
    int dst = (i < E) ? ei[E + i] : (i - E);
    atomicAdd(&counts[dst], 1);
}

__global__ __launch_bounds__(512) void scan_block_kernel(const int* __restrict__ counts,
                                                         int* __restrict__ row_ptr,
                                                         int* __restrict__ blk_sums) {
    __shared__ int s[512];
    int t = threadIdx.x;
    int i = blockIdx.x * 512 + t;
    int v = (i < N) ? counts[i] : 0;
    s[t] = v;
    __syncthreads();
    for (int off = 1; off < 512; off <<= 1) {
        int add = (t >= off) ? s[t - off] : 0;
        __syncthreads();
        s[t] += add;
        __syncthreads();
    }
    if (i < N) row_ptr[i] = s[t] - v;                 // exclusive within block
    if (t == 511) blk_sums[blockIdx.x] = s[511];
}

__global__ __launch_bounds__(128) void scan_sums_kernel(int* __restrict__ blk, int nb) {
    __shared__ int s[128];
    int t = threadIdx.x;
    int v = (t < nb) ? blk[t] : 0;
    s[t] = v;
    __syncthreads();
    for (int off = 1; off < 128; off <<= 1) {
        int add = (t >= off) ? s[t - off] : 0;
        __syncthreads();
        s[t] += add;
        __syncthreads();
    }
    if (t < nb) blk[t] = s[t] - v;                    // exclusive block offsets
}

__global__ void scan_add_kernel(int* __restrict__ row_ptr, const int* __restrict__ blk) {
    int i = blockIdx.x * blockDim.x + threadIdx.x;
    if (i < N) row_ptr[i] += blk[i >> 9];
    if (i == 0) row_ptr[N] = E2;
}

__global__ void scatter_kernel(const int* __restrict__ ei, const int* __restrict__ row_ptr,
                               int* __restrict__ wp, int* __restrict__ col_idx) {
    int i = blockIdx.x * blockDim.x + threadIdx.x;
    if (i >= E2) return;
    int src, dst;
    if (i < E) { src = ei[i]; dst = ei[E + i]; }
    else       { src = i - E; dst = i - E; }
    int pos = row_ptr[dst] + atomicAdd(&wp[dst], 1);
    col_idx[pos] = src;
}

// ---------- pack 10 weight matrices into MFMA B-fragment order (hi bf16 only) ----------
// B frag for 16x16x32: lane holds B[k = ks*32 + (lane>>4)*8 + j][n = nb*16 + (lane&15)],
// j=0..7. Packed index: (mat*2048 + (ks*8+nb)*64 + lane)*8 + j  -> lane-contiguous 16B.
__global__ __launch_bounds__(256) void pack_w_kernel(
        const float* __restrict__ Wl, const float* __restrict__ Wr,
        const float* __restrict__ Wres, const float* __restrict__ Wout,
        hbf* __restrict__ Wph) {
    int gid = blockIdx.x * 256 + threadIdx.x;        // 10 * 16384
    int mat = gid >> 14;
    int d = gid & 16383;
    const float* W;
    if (mat < 3)      W = Wl + (size_t)mat * 16384;
    else if (mat < 6) W = Wr + (size_t)(mat - 3) * 16384;
    else if (mat < 9) W = Wres + (size_t)(mat - 6) * 16384;
    else              W = Wout;
    int j = d & 7, lane = (d >> 3) & 63, nb = (d >> 9) & 7, ks = d >> 12;
    int k = ks * 32 + ((lane >> 4) * 8) + j;
    int n = nb * 16 + (lane & 15);
    Wph[gid] = __float2bfloat16(W[k * D + n]);
}

// ---------- fused 3-matrix MFMA GEMM, one 64-row tile per block ----------
// X = leaky(bn(x)) if sums else x; bn scale/shift derived in-block from sums+gamma+beta.
// xl = bf16(X@Wl), xr = bf16(X@Wr), y = X@Wres + bias.  In-place-safe (x == y): tile
// snapshot into LDS before any store; each tile owned by one block.
// Wave w owns n-blocks {2w, 2w+1}; B frags (24) in VGPRs, loaded once per block.
// 2-term split: X@W ~= Xh@Wh + Xl@Wh (W bf16-rounded).
__global__ __launch_bounds__(256) void gemm3_mfma_kernel(
        const float* x, const float* __restrict__ sums,
        const float* __restrict__ gamma, const float* __restrict__ beta,
        const hbf* __restrict__ Wph,
        int mL, int mR, int mS, const float* __restrict__ bias,
        hbf* __restrict__ xl, hbf* __restrict__ xr, float* y) {
    __shared__ float xs[64][133];                     // +5 pad: 2-way max bank aliasing
    __shared__ float ssl[2][128];                     // bn scale/shift
    int t = threadIdx.x;
    int wave = t >> 6;
    int lane = t & 63;
    int nb0 = wave * 2;                               // this wave's two n-blocks
    int row0 = blockIdx.x * 64;

    if (sums && t < 128) {                            // fold of old bn_finalize
        float mean = sums[t] * (1.0f / N);
        float var = fmaxf(sums[D + t] * (1.0f / N) - mean * mean, 0.f);
        float sc = gamma[t] * rsqrtf(var + BN_EPS);
        ssl[0][t] = sc;
        ssl[1][t] = beta[t] - mean * sc;
    }

    const bf16x8_t* B = (const bf16x8_t*)Wph;
    bf16x8_t bL[4][2], bR[4][2], bS[4][2];            // 24 frags = 96 VGPRs, loaded once
#pragma unroll
    for (int ks = 0; ks < 4; ++ks)
#pragma unroll
        for (int j = 0; j < 2; ++j) {
            int bo = (ks * 8 + nb0 + j) * 64 + lane;
            bL[ks][j] = B[mL * 2048 + bo];
            bR[ks][j] = B[mR * 2048 + bo];
            bS[ks][j] = B[mS * 2048 + bo];
        }
    __syncthreads();                                  // ssl visible

    int cg = (t & 31) * 4;                            // staging col group
    {
        float sc_[4] = {1.f, 1.f, 1.f, 1.f}, sh_[4] = {0.f, 0.f, 0.f, 0.f};
        if (sums) {
#pragma unroll
            for (int j = 0; j < 4; ++j) { sc_[j] = ssl[0][cg + j]; sh_[j] = ssl[1][cg + j]; }
        }
        const float4* x4 = (const float4*)(x + (size_t)row0 * D);
        for (int i = t; i < 64 * 32; i += 256) {
            int r = i >> 5;
            float4 v = make_float4(0.f, 0.f, 0.f, 0.f);
            if (row0 + r < N) {
                v = x4[i];
                if (sums) {
                    v.x = fmaf(v.x, sc_[0], sh_[0]); v.x = fmaxf(v.x, SLOPE * v.x);
                    v.y = fmaf(v.y, sc_[1], sh_[1]); v.y = fmaxf(v.y, SLOPE * v.y);
                    v.z = fmaf(v.z, sc_[2], sh_[2]); v.z = fmaxf(v.z, SLOPE * v.z);
                    v.w = fmaf(v.w, sc_[3], sh_[3]); v.w = fmaxf(v.w, SLOPE * v.w);
                }
            }
            *(float4*)&xs[r][cg] = v;
        }
    }
    __syncthreads();

    int col = lane & 15;
    int koff = (lane >> 4) * 8;
    for (int mm = 0; mm < 4; ++mm) {
        int mrow = mm * 16 + (lane & 15);
        f32x4_t aL[2], aR[2], aS[2];
#pragma unroll
        for (int j = 0; j < 2; ++j) {
            aL[j] = (f32x4_t)0.f; aR[j] = (f32x4_t)0.f; aS[j] = (f32x4_t)0.f;
        }
#pragma unroll
        for (int ks = 0; ks < 4; ++ks) {
            const float* src = &xs[mrow][ks * 32 + koff];
            float4 f0 = *(const float4*)src;
            float4 f1 = *(const float4*)(src + 4);
            float f[8] = {f0.x, f0.y, f0.z, f0.w, f1.x, f1.y, f1.z, f1.w};
            bf16x8_t ah, al;
#pragma unroll
            for (int j = 0; j < 8; ++j) {
                short hi = f2bf(f[j]);
                unsigned int hu = ((unsigned int)(unsigned short)hi) << 16;
                ah[j] = hi;
                al[j] = f2bf(f[j] - __uint_as_float(hu));
            }
#pragma unroll
            for (int j = 0; j < 2; ++j) {
                aL[j] = __builtin_amdgcn_mfma_f32_16x16x32_bf16(ah, bL[ks][j], aL[j], 0, 0, 0);
                aL[j] = __builtin_amdgcn_mfma_f32_16x16x32_bf16(al, bL[ks][j], aL[j], 0, 0, 0);
                aR[j] = __builtin_amdgcn_mfma_f32_16x16x32_bf16(ah, bR[ks][j], aR[j], 0, 0, 0);
                aR[j] = __builtin_amdgcn_mfma_f32_16x16x32_bf16(al, bR[ks][j], aR[j], 0, 0, 0);
                aS[j] = __builtin_amdgcn_mfma_f32_16x16x32_bf16(ah, bS[ks][j], aS[j], 0, 0, 0);
                aS[j] = __builtin_amdgcn_mfma_f32_16x16x32_bf16(al, bS[ks][j], aS[j], 0, 0, 0);
            }
        }
        // C/D layout: col = lane&15, row = (lane>>4)*4 + r
        int rowq = row0 + mm * 16 + (lane >> 4) * 4;
#pragma unroll
        for (int j = 0; j < 2; ++j) {
            int n = (nb0 + j) * 16 + col;
            float bv = bias[n];
#pragma unroll
            for (int r = 0; r < 4; ++r) {
                int row = rowq + r;
                if (row < N) {
                    xl[(size_t)row * D + n] = __float2bfloat16(aL[j][r]);
                    xr[(size_t)row * D + n] = __float2bfloat16(aR[j][r]);
                    y[(size_t)row * D + n]  = aS[j][r] + bv;
                }
            }
        }
    }
}

// ---------- final linear via MFMA, same structure (BN+leaky on load) ----------
__global__ __launch_bounds__(256) void gemm_out_mfma_kernel(
        const float* __restrict__ x, const float* __restrict__ sums,
        const float* __restrict__ gamma, const float* __restrict__ beta,
        const hbf* __restrict__ Wph, const float* __restrict__ b,
        float* __restrict__ out) {
    __shared__ float xs[64][133];
    __shared__ float ssl[2][128];
    int t = threadIdx.x;
    int wave = t >> 6;
    int lane = t & 63;
    int nb0 = wave * 2;
    int row0 = blockIdx.x * 64;

    if (t < 128) {
        float mean = sums[t] * (1.0f / N);
        float var = fmaxf(sums[D + t] * (1.0f / N) - mean * mean, 0.f);
        float sc = gamma[t] * rsqrtf(var + BN_EPS);
        ssl[0][t] = sc;
        ssl[1][t] = beta[t] - mean * sc;
    }

    const bf16x8_t* B = (const bf16x8_t*)Wph + 9 * 2048;      // matrix 9 = Wout
    bf16x8_t bW[4][2];
#pragma unroll
    for (int ks = 0; ks < 4; ++ks)
#pragma unroll
        for (int j = 0; j < 2; ++j)
            bW[ks][j] = B[(ks * 8 + nb0 + j) * 64 + lane];
    __syncthreads();

    int cg = (t & 31) * 4;
    {
        float sc_[4], sh_[4];
#pragma unroll
        for (int j = 0; j < 4; ++j) { sc_[j] = ssl[0][cg + j]; sh_[j] = ssl[1][cg + j]; }
        const float4* x4 = (const float4*)(x + (size_t)row0 * D);
        for (int i = t; i < 64 * 32; i += 256) {
            int r = i >> 5;
            float4 v = make_float4(0.f, 0.f, 0.f, 0.f);
            if (row0 + r < N) {
                v = x4[i];
                v.x = fmaf(v.x, sc_[0], sh_[0]); v.x = fmaxf(v.x, SLOPE * v.x);
                v.y = fmaf(v.y, sc_[1], sh_[1]); v.y = fmaxf(v.y, SLOPE * v.y);
                v.z = fmaf(v.z, sc_[2], sh_[2]); v.z = fmaxf(v.z, SLOPE * v.z);
                v.w = fmaf(v.w, sc_[3], sh_[3]); v.w = fmaxf(v.w, SLOPE * v.w);
            }
            *(float4*)&xs[r][cg] = v;
        }
    }
    __syncthreads();

    int col = lane & 15;
    int koff = (lane >> 4) * 8;
    for (int mm = 0; mm < 4; ++mm) {
        int mrow = mm * 16 + (lane & 15);
        f32x4_t acc[2];
        acc[0] = (f32x4_t)0.f; acc[1] = (f32x4_t)0.f;
#pragma unroll
        for (int ks = 0; ks < 4; ++ks) {
            const float* src = &xs[mrow][ks * 32 + koff];
            float4 f0 = *(const float4*)src;
            float4 f1 = *(const float4*)(src + 4);
            float f[8] = {f0.x, f0.y, f0.z, f0.w, f1.x, f1.y, f1.z, f1.w};
            bf16x8_t ah, al;
#pragma unroll
            for (int j = 0; j < 8; ++j) {
                short hi = f2bf(f[j]);
                unsigned int hu = ((unsigned int)(unsigned short)hi) << 16;
                ah[j] = hi;
                al[j] = f2bf(f[j] - __uint_as_float(hu));
            }
#pragma unroll
            for (int j = 0; j < 2; ++j) {
                acc[j] = __builtin_amdgcn_mfma_f32_16x16x32_bf16(ah, bW[ks][j], acc[j], 0, 0, 0);
                acc[j] = __builtin_amdgcn_mfma_f32_16x16x32_bf16(al, bW[ks][j], acc[j], 0, 0, 0);
            }
        }
        int rowq = row0 + mm * 16 + (lane >> 4) * 4;
#pragma unroll
        for (int j = 0; j < 2; ++j) {
            int n = (nb0 + j) * 16 + col;
            float bv = b[n];
#pragma unroll
            for (int r = 0; r < 4; ++r) {
                int row = rowq + r;
                if (row < N) out[(size_t)row * D + n] = acc[j][r] + bv;
            }
        }
    }
}

// ---------- GATv2 aggregation: wave/node, two edges per wave, 2-LEVEL pipeline ----------
// r14 post-mortem: VALUBusy fell to 59% — the stall is the chained load
// col_idx -> address -> xl gather inside the prefetch (col_idx is per-lane,
// ~200cyc, feeding the gather back-to-back). Fix: keep each buffer's NEXT refill
// col_idx values in registers (c0/c1, loaded one group-pair earlier = distance 16);
// the xl gather then issues immediately from registers. Lane covers 4 channels
// (sub=lane&31), half=lane>>5 picks the edge of a pair; 3-level shuffle tree.
// No online max (scores BN-bounded). Fixed-size buffers, literal indices only
// (r10: dynamic indexing demotes to LDS). log2-domain scores -> exp2.
__global__ __launch_bounds__(256) void gat_kernel(
        const hbf* __restrict__ xl, const hbf* __restrict__ xr,
        float* y, const int* __restrict__ row_ptr,
        const int* __restrict__ col_idx, const float* __restrict__ att) {
    int wave = threadIdx.x >> 6;
    int lane = threadIdx.x & 63;
    int half = lane >> 5;                             // which edge of the pair
    int sub  = lane & 31;                             // channels 4*sub .. 4*sub+3
    int v = blockIdx.x * 4 + wave;
    const uint2* xlp = (const uint2*)xl;              // 4 bf16 per lane
    const uint2* xrp = (const uint2*)xr;
    uint2 xru = xrp[(size_t)v * 32 + sub];
    v2f xr_a = bfpair_to_v2(xru.x);
    v2f xr_b = bfpair_to_v2(xru.y);
    float4 a4 = ((const float4*)att)[sub];            // head = sub/8
    v2f a_a; a_a.x = a4.x * LOG2E; a_a.y = a4.y * LOG2E;
    v2f a_b; a_b.x = a4.z * LOG2E; a_b.y = a4.w * LOG2E;
    int beg = row_ptr[v], end = row_ptr[v + 1];
    float l = 0.f;
    v2f acc_a = {0.f, 0.f};
    v2f acc_b = {0.f, 0.f};

    // data buffers for groups G,G+1; col_idx registers for their refills (dist 8)
    uint2 u0[2], u1[2];
    int c0[2], c1[2];
    u0[0] = xlp[(size_t)col_idx[min(beg + 0 + half, end - 1)] * 32 + sub];
    u0[1] = xlp[(size_t)col_idx[min(beg + 2 + half, end - 1)] * 32 + sub];
    u1[0] = xlp[(size_t)col_idx[min(beg + 4 + half, end - 1)] * 32 + sub];
    u1[1] = xlp[(size_t)col_idx[min(beg + 6 + half, end - 1)] * 32 + sub];
    c0[0] = col_idx[min(beg + 8 + half, end - 1)];
    c0[1] = col_idx[min(beg + 10 + half, end - 1)];
    c1[0] = col_idx[min(beg + 12 + half, end - 1)];
    c1[1] = col_idx[min(beg + 14 + half, end - 1)];

    int idx = beg;
    auto process4 = [&](uint2 (&buf)[2], int (&cid)[2]) {
        v2f xa0 = bfpair_to_v2(buf[0].x);
        v2f xb0 = bfpair_to_v2(buf[0].y);
        v2f xa1 = bfpair_to_v2(buf[1].x);
        v2f xb1 = bfpair_to_v2(buf[1].y);
        // refill data at distance 8 from pre-loaded col_idx (no chained latency)
        buf[0] = xlp[(size_t)cid[0] * 32 + sub];
        buf[1] = xlp[(size_t)cid[1] * 32 + sub];
        // reload col_idx for this buffer's NEXT refill (distance 16)
        cid[0] = col_idx[min(idx + 16 + half, end - 1)];
        cid[1] = col_idx[min(idx + 18 + half, end - 1)];

        v2f pa0 = xa0 + xr_a, pb0 = xb0 + xr_b;       // v_pk_add_f32
        v2f pa1 = xa1 + xr_a, pb1 = xb1 + xr_b;
        pa0 = __builtin_elementwise_max(pa0, pa0 * SLOPE);
        pb0 = __builtin_elementwise_max(pb0, pb0 * SLOPE);
        pa1 = __builtin_elementwise_max(pa1, pa1 * SLOPE);
        pb1 = __builtin_elementwise_max(pb1, pb1 * SLOPE);
        v2f t0 = pa0 * a_a; t0 = pb0 * a_b + t0;      // pk_mul + pk_fma
        v2f t1 = pa1 * a_a; t1 = pb1 * a_b + t1;
        float s0 = t0.x + t0.y;
        float s1 = t1.x + t1.y;
        s0 += __shfl_xor(s0, 1);  s1 += __shfl_xor(s1, 1);
        s0 += __shfl_xor(s0, 2);  s1 += __shfl_xor(s1, 2);
        s0 += __shfl_xor(s0, 4);  s1 += __shfl_xor(s1, 4);
        float w0 = fast_exp2(s0);
        float w1 = fast_exp2(s1);
        l += w0 + w1;
        acc_a = xa0 * w0 + acc_a;                     // v_pk_fma_f32
        acc_b = xb0 * w0 + acc_b;
        acc_a = xa1 * w1 + acc_a;
        acc_b = xb1 * w1 + acc_b;
    };

    while (idx + 3 < end) {
        process4(u0, c0);
        idx += 4;
        if (idx + 3 >= end) break;
        process4(u1, c1);
        idx += 4;
    }
    for (; idx < end; ++idx) {                        // tail <=3: both halves same edge
        uint2 xu = xlp[(size_t)col_idx[idx] * 32 + sub];
        v2f xa = bfpair_to_v2(xu.x);
        v2f xb = bfpair_to_v2(xu.y);
        v2f pa = xa + xr_a, pb = xb + xr_b;
        pa = __builtin_elementwise_max(pa, pa * SLOPE);
        pb = __builtin_elementwise_max(pb, pb * SLOPE);
        v2f tt = pa * a_a; tt = pb * a_b + tt;
        float sa = tt.x + tt.y;
        sa += __shfl_xor(sa, 1);
        sa += __shfl_xor(sa, 2);
        sa += __shfl_xor(sa, 4);
        float wa = half ? 0.f : fast_exp2(sa);        // avoid double count
        l += wa;
        acc_a = xa * wa + acc_a;
        acc_b = xb * wa + acc_b;
    }
    // combine the two halves (each held one edge of every pair)
    l += __shfl_xor(l, 32);
    acc_a.x += __shfl_xor(acc_a.x, 32);
    acc_a.y += __shfl_xor(acc_a.y, 32);
    acc_b.x += __shfl_xor(acc_b.x, 32);
    acc_b.y += __shfl_xor(acc_b.y, 32);
    if (half == 0) {
        float rl = 1.f / l;
        size_t o = (size_t)v * 32 + sub;
        float4 yv = ((const float4*)y)[o];
        yv.x = fmaf(acc_a.x, rl, yv.x);               // agg + res(+bias)
        yv.y = fmaf(acc_a.y, rl, yv.y);
        yv.z = fmaf(acc_b.x, rl, yv.z);
        yv.w = fmaf(acc_b.y, rl, yv.w);
        ((float4*)y)[o] = yv;
    }
}

// ---------- BatchNorm stats: coalesced float4, LDS reduce, atomics ----------
__global__ __launch_bounds__(256) void bn_stats_kernel(const float* __restrict__ y,
                                                       float* __restrict__ sums) {
    __shared__ float ls[256][4];
    __shared__ float ls2[256][4];
    int t = threadIdx.x;
    float4 s = make_float4(0.f, 0.f, 0.f, 0.f);
    float4 s2 = make_float4(0.f, 0.f, 0.f, 0.f);
    const float4* y4 = (const float4*)y;
    for (int i = blockIdx.x * 256 + t; i < N * D / 4; i += gridDim.x * 256) {
        float4 v = y4[i];                             // cols 4*(t&31)..+3 (fixed)
        s.x += v.x; s.y += v.y; s.z += v.z; s.w += v.w;
        s2.x = fmaf(v.x, v.x, s2.x); s2.y = fmaf(v.y, v.y, s2.y);
        s2.z = fmaf(v.z, v.z, s2.z); s2.w = fmaf(v.w, v.w, s2.w);
    }
    ls[t][0] = s.x;  ls[t][1] = s.y;  ls[t][2] = s.z;  ls[t][3] = s.w;
    ls2[t][0] = s2.x; ls2[t][1] = s2.y; ls2[t][2] = s2.z; ls2[t][3] = s2.w;
    __syncthreads();
    if (t < D) {
        int g = t >> 2, e = t & 3;
        float a = 0.f, b = 0.f;
#pragma unroll
        for (int j = 0; j < 8; ++j) {
            a += ls[g + 32 * j][e];
            b += ls2[g + 32 * j][e];
        }
        atomicAdd(&sums[t], a);
        atomicAdd(&sums[D + t], b);
    }
}

extern "C" void kernel_launch(void* const* d_in, const int* in_sizes, int n_in,
                              void* d_out, int out_size, void* d_ws, size_t ws_size,
                              hipStream_t stream) {
    const float* x_in  = (const float*)d_in[0];
    const int*   ei    = (const int*)d_in[1];
    const float* Wl    = (const float*)d_in[2];
    const float* Wr    = (const float*)d_in[3];
    const float* att   = (const float*)d_in[4];
    const float* bias  = (const float*)d_in[5];
    const float* Wres  = (const float*)d_in[6];
    const float* gamma = (const float*)d_in[7];
    const float* beta  = (const float*)d_in[8];
    const float* Wout  = (const float*)d_in[9];
    const float* bout  = (const float*)d_in[10];
    float* out = (float*)d_out;

    char* ws = (char*)d_ws;
    size_t off = 0;
    auto alloc = [&](size_t bytes) {
        void* p = ws + off;
        off = (off + bytes + 255) & ~(size_t)255;
        return p;
    };
    hbf*   xl       = (hbf*)alloc((size_t)N * D * sizeof(hbf));
    hbf*   xr       = (hbf*)alloc((size_t)N * D * sizeof(hbf));
    float* y        = (float*)alloc((size_t)N * D * sizeof(float));
    hbf*   Wph      = (hbf*)alloc((size_t)10 * D * D * sizeof(hbf));
    int*   row_ptr  = (int*)alloc((size_t)(N + 1) * sizeof(int));
    int*   col_idx  = (int*)alloc((size_t)E2 * sizeof(int));
    int*   counts   = (int*)alloc((size_t)N * sizeof(int));   // reused as write ptr
    int*   blk_sums = (int*)alloc(128 * sizeof(int));
    float* sums     = (float*)alloc(3 * 2 * D * sizeof(float));  // per-layer bn sums

    const int NB = (N + 511) / 512;                  // 98 scan blocks

    // CSR build + weight packing (+ one upfront zero of all 3 bn-sum buffers)
    (void)hipMemsetAsync(counts, 0, (size_t)N * sizeof(int), stream);
    (void)hipMemsetAsync(sums, 0, 3 * 2 * D * sizeof(float), stream);
    count_kernel<<<(E2 + 255) / 256, 256, 0, stream>>>(ei, counts);
    pack_w_kernel<<<10 * 16384 / 256, 256, 0, stream>>>(Wl, Wr, Wres, Wout, Wph);
    scan_block_kernel<<<NB, 512, 0, stream>>>(counts, row_ptr, blk_sums);
    scan_sums_kernel<<<1, 128, 0, stream>>>(blk_sums, NB);
    scan_add_kernel<<<(N + 255) / 256, 256, 0, stream>>>(row_ptr, blk_sums);
    (void)hipMemsetAsync(counts, 0, (size_t)N * sizeof(int), stream);
    scatter_kernel<<<(E2 + 255) / 256, 256, 0, stream>>>(ei, row_ptr, counts, col_idx);

    for (int i = 0; i < L; ++i) {
        const float* xin = (i == 0) ? x_in : y;      // in-place (tile snapshot) for 1,2
        const float* sm  = (i == 0) ? nullptr : sums + (size_t)(i - 1) * 2 * D;
        const float* ga  = (i == 0) ? nullptr : gamma + (size_t)(i - 1) * D;
        const float* be  = (i == 0) ? nullptr : beta + (size_t)(i - 1) * D;
        gemm3_mfma_kernel<<<TILES, 256, 0, stream>>>(xin, sm, ga, be, Wph,
                                                     i, 3 + i, 6 + i,
                                                     bias + (size_t)i * D, xl, xr, y);
        gat_kernel<<<N / 4, 256, 0, stream>>>(xl, xr, y, row_ptr, col_idx,
                                              att + (size_t)i * H * C);
        bn_stats_kernel<<<512, 256, 0, stream>>>(y, sums + (size_t)i * 2 * D);
    }

    gemm_out_mfma_kernel<<<TILES, 256, 0, stream>>>(y, sums + (size_t)2 * 2 * D,
                                                    gamma + (size_t)2 * D,
                                                    beta + (size_t)2 * D, Wph, bout, out);
}